// Round 4
// baseline (1340.986 us; speedup 1.0000x reference)
//
#include <hip/hip_runtime.h>
#include <hip/hip_fp16.h>
#include <math.h>

// Problem constants (from reference): N=100000, E=1600000, F_IN=8, H=128,
// L=4, E_FEAT=16, G=256, OUT=256. N/E derived from in_sizes at launch.
#define GG 256

typedef __attribute__((ext_vector_type(8))) short short8;
typedef __attribute__((ext_vector_type(4))) float f32x4;
typedef _Float16 half2v __attribute__((ext_vector_type(2)));
typedef __attribute__((ext_vector_type(4))) unsigned uint4v;
typedef __attribute__((ext_vector_type(8))) unsigned uint8v;

__device__ __forceinline__ unsigned short f2bf(float x) {
  union { float f; unsigned u; } v; v.f = x;
  unsigned r = v.u + 0x7fff + ((v.u >> 16) & 1);   // round-to-nearest-even
  return (unsigned short)(r >> 16);
}

__device__ __forceinline__ unsigned pack_h2(float a, float b) {
  __half2 h = __floats2half2_rn(a, b);
  return *(unsigned*)&h;
}

// v_dot2_f32_f16: D = a.lo*b.lo + a.hi*b.hi + c  (f32 accumulate)
__device__ __forceinline__ float fdot2u(unsigned a, unsigned b, float c) {
  half2v av, bv;
  __builtin_memcpy(&av, &a, 4);
  __builtin_memcpy(&bv, &b, 4);
  return __builtin_amdgcn_fdot2(av, bv, c, false);
}

// scalar loads (wave-uniform addresses) — SMEM path, SALU addressing
__device__ __forceinline__ uint4v sload4(const void* p) {
  uint4v r;
  asm volatile("s_load_dwordx4 %0, %1, 0x0"
               : "=s"(r) : "s"((unsigned long long)p));
  return r;
}
__device__ __forceinline__ uint8v sload8(const void* p) {
  uint8v r;
  asm volatile("s_load_dwordx8 %0, %1, 0x0"
               : "=s"(r) : "s"((unsigned long long)p));
  return r;
}
__device__ __forceinline__ void swait() {
  asm volatile("s_waitcnt lgkmcnt(0)" ::: "memory");
  __builtin_amdgcn_sched_barrier(0);   // rule #18: pin consumers after the wait
}

// ---------- h = x @ emb_W + emb_b  ([N,8]@[8,128]); also writes bf16 shadow ----------
__global__ __launch_bounds__(256) void k_emb(const float* __restrict__ x,
    const float* __restrict__ W, const float* __restrict__ b,
    float* __restrict__ h, unsigned short* __restrict__ hb, int N) {
  int idx = blockIdx.x * 256 + threadIdx.x;      // one float4 of output per thread
  if (idx >= N * 32) return;
  int n = idx >> 5, q = idx & 31;
  const float* xr = x + (size_t)n * 8;
  float xs[8];
#pragma unroll
  for (int k = 0; k < 8; ++k) xs[k] = xr[k];
  float4 acc = ((const float4*)b)[q];
#pragma unroll
  for (int k = 0; k < 8; ++k) {
    float4 w = ((const float4*)(W + (size_t)k * 128))[q];
    acc.x += xs[k] * w.x; acc.y += xs[k] * w.y;
    acc.z += xs[k] * w.z; acc.w += xs[k] * w.w;
  }
  ((float4*)h)[idx] = acc;
  ushort4 hv4 = make_ushort4(f2bf(acc.x), f2bf(acc.y), f2bf(acc.z), f2bf(acc.w));
  *(ushort4*)(hb + (size_t)idx * 4) = hv4;
}

// ---------- edge weights -> packed fp16 PAIRS along k (dot2 layout) ----------
// eWp[l][k][c] = half2( W[l][2k][c], W[l][2k+1][c] ),  k=0..7, c=0..127
__global__ __launch_bounds__(256) void k_wconv(const float* __restrict__ eW,
    unsigned* __restrict__ eWp) {              // 4*8*128 = 4096 pairs
  int i = blockIdx.x * 256 + threadIdx.x;
  if (i >= 4096) return;
  int c = i & 127, k = (i >> 7) & 7, l = i >> 10;
  const float* base = eW + ((size_t)(l * 16 + 2 * k) * 128 + c);
  eWp[i] = pack_h2(base[0], base[128]);
}

// ---------- transpose nn_W to bf16: WT[l][n][k] = bf16(nn_W[l][k][n]) ----------
__global__ __launch_bounds__(256) void k_nnconv(const float* __restrict__ W,
    unsigned short* __restrict__ WT) {
  int i = blockIdx.x * 256 + threadIdx.x;    // i = ((l*128)+k)*128 + n
  if (i >= 4 * 128 * 128) return;
  int n = i & 127, k = (i >> 7) & 127, l = i >> 14;
  WT[((size_t)(l * 128 + n)) * 128 + k] = f2bf(W[i]);
}

// ---------- convert edge attrs to fp16 in ORIGINAL edge order (coalesced) ----------
__global__ __launch_bounds__(256) void k_aconv(const float* __restrict__ attr,
    uint4* __restrict__ attr16c, int E2) {   // E2 = E*2 output uint4s
  int i = blockIdx.x * 256 + threadIdx.x;
  if (i >= E2) return;
  float4 a0 = ((const float4*)attr)[(size_t)i * 2];
  float4 a1 = ((const float4*)attr)[(size_t)i * 2 + 1];
  uint4 o;
  o.x = pack_h2(a0.x, a0.y); o.y = pack_h2(a0.z, a0.w);
  o.z = pack_h2(a1.x, a1.y); o.w = pack_h2(a1.z, a1.w);
  attr16c[i] = o;
}

// ---------- CSR build ----------
__global__ void k_hist(const int* __restrict__ dst, int* __restrict__ deg, int E) {
  int e = blockIdx.x * blockDim.x + threadIdx.x;
  if (e < E) atomicAdd(&deg[dst[e]], 1);
}

__global__ __launch_bounds__(256) void k_scan_reduce(const int* __restrict__ deg,
    int* __restrict__ bsum, int N) {
  __shared__ int sd[256];
  int i = blockIdx.x * 256 + threadIdx.x;
  sd[threadIdx.x] = (i < N) ? deg[i] : 0;
  __syncthreads();
  for (int s = 128; s > 0; s >>= 1) {
    if (threadIdx.x < s) sd[threadIdx.x] += sd[threadIdx.x + s];
    __syncthreads();
  }
  if (threadIdx.x == 0) bsum[blockIdx.x] = sd[0];
}

// single-block exclusive scan over nb (<=512) block sums
__global__ __launch_bounds__(512) void k_scan_mid(int* bsum, int nb) {
  __shared__ int sd[512];
  int t = threadIdx.x;
  int v = (t < nb) ? bsum[t] : 0;
  sd[t] = v; __syncthreads();
  for (int d = 1; d < 512; d <<= 1) {
    int xv = (t >= d) ? sd[t - d] : 0;
    __syncthreads();
    sd[t] += xv;
    __syncthreads();
  }
  if (t < nb) bsum[t] = sd[t] - v;   // exclusive
}

__global__ __launch_bounds__(256) void k_scan_final(const int* __restrict__ deg,
    const int* __restrict__ bsum, int* __restrict__ offs,
    int* __restrict__ cursor, int N) {
  __shared__ int sd[256];
  int t = threadIdx.x;
  int i = blockIdx.x * 256 + t;
  int v = (i < N) ? deg[i] : 0;
  sd[t] = v; __syncthreads();
  for (int d = 1; d < 256; d <<= 1) {           // Hillis-Steele inclusive scan
    int xv = (t >= d) ? sd[t - d] : 0;
    __syncthreads();
    sd[t] += xv;
    __syncthreads();
  }
  int off = bsum[blockIdx.x] + sd[t] - v;       // exclusive
  if (i < N) {
    offs[i] = off; cursor[i] = off;
    if (i == N - 1) offs[N] = off + v;
  }
}

// scatter ONLY small records: csrc[pos]=src, perm[pos]=e  (8 B/edge scattered)
__global__ void k_fillperm(const int* __restrict__ src, const int* __restrict__ dst,
    int* __restrict__ cursor, int* __restrict__ csrc, int* __restrict__ perm, int E) {
  int e = blockIdx.x * blockDim.x + threadIdx.x;
  if (e >= E) return;
  int d = dst[e];
  int pos = atomicAdd(&cursor[d], 1);
  csrc[pos] = src[e];
  perm[pos] = e;
}

// gather-permute fp16 attrs into CSR order: random READS (L3), coalesced writes
__global__ __launch_bounds__(256) void k_permgather(const int* __restrict__ perm,
    const uint4* __restrict__ attr16c, uint4* __restrict__ cattr16, int E) {
  int pos = blockIdx.x * 256 + threadIdx.x;
  if (pos >= E) return;
  int e = perm[pos];
  uint4 a0 = attr16c[(size_t)e * 2];
  uint4 a1 = attr16c[(size_t)e * 2 + 1];
  cattr16[(size_t)pos * 2] = a0;
  cattr16[(size_t)pos * 2 + 1] = a1;
}

// ---------- graph boundaries (batch is sorted) ----------
__global__ void k_gstart(const int* __restrict__ batch, int* __restrict__ gstart,
                         int N, int Gn) {
  int i = blockIdx.x * blockDim.x + threadIdx.x;
  if (i >= N) return;
  int b = batch[i];
  if (i == 0) { for (int g = 0; g <= b; ++g) gstart[g] = 0; }
  else { int bp = batch[i - 1]; for (int g = bp + 1; g <= b; ++g) gstart[g] = i; }
  if (i == N - 1) { for (int g = b + 1; g <= Gn; ++g) gstart[g] = N; }
}

// ---------- fused edge embed + gather + relu + aggregate (v4: pipelined) ----------
// hpa16[n] = bf16( h[n] + sum_j relu( attr[j]@edge_W + edge_b + h[src[j]] ) )
// Super-groups of 8 edges: one s_load_dwordx8 for src ids (drained once / 8
// edges, next super-group's s_load issued BEFORE the trailing computes);
// attrs are VMEM broadcast loads (divergent-zero mbcnt defeats scalarization)
// so attrs+gathers pipeline under compiler-counted vmcnt across groups.
__global__ __launch_bounds__(256, 4) void k_edge_agg(const float* __restrict__ h,
    const unsigned* __restrict__ hb32,       // bf16 shadow viewed as uint
    const uint4* __restrict__ cattr16, const int* __restrict__ csrc,
    const int* __restrict__ offs, const unsigned* __restrict__ eWp,
    const float* __restrict__ eb, unsigned* __restrict__ hpa16,
    float* __restrict__ cstats, int N) {
  int t = threadIdx.x;
  if (blockIdx.x == 0) cstats[t] = 0.f;    // 256 floats: colsum|colsumsq
  int l = t & 63;                           // lane -> columns 2l, 2l+1
  int wid = blockIdx.x * 4 + (t >> 6);
  int nw = gridDim.x * 4;
  unsigned dz = __builtin_amdgcn_mbcnt_lo(0u, 0u);  // always 0, looks divergent
  uint2 wp[8];                              // wp[k].x pairs for col 2l, .y for 2l+1
#pragma unroll
  for (int k = 0; k < 8; ++k) wp[k] = *(const uint2*)&eWp[k * 128 + 2 * l];
  float2 bias = *(const float2*)(eb + 2 * l);
  const unsigned* hb_l = hb32 + l;          // + s*64 per edge (row = 64 uints)

#define EDGE_V(P0, P1, UU, AX, AY)                                          \
  {                                                                         \
    float e0 = bias.x, e1 = bias.y;                                         \
    e0 = fdot2u(P0.x, wp[0].x, e0); e1 = fdot2u(P0.x, wp[0].y, e1);         \
    e0 = fdot2u(P0.y, wp[1].x, e0); e1 = fdot2u(P0.y, wp[1].y, e1);         \
    e0 = fdot2u(P0.z, wp[2].x, e0); e1 = fdot2u(P0.z, wp[2].y, e1);         \
    e0 = fdot2u(P0.w, wp[3].x, e0); e1 = fdot2u(P0.w, wp[3].y, e1);         \
    e0 = fdot2u(P1.x, wp[4].x, e0); e1 = fdot2u(P1.x, wp[4].y, e1);         \
    e0 = fdot2u(P1.y, wp[5].x, e0); e1 = fdot2u(P1.y, wp[5].y, e1);         \
    e0 = fdot2u(P1.z, wp[6].x, e0); e1 = fdot2u(P1.z, wp[6].y, e1);         \
    e0 = fdot2u(P1.w, wp[7].x, e0); e1 = fdot2u(P1.w, wp[7].y, e1);         \
    union { unsigned uu; float ff; } c0, c1;                                \
    c0.uu = (UU) << 16; c1.uu = (UU) & 0xffff0000u;                         \
    AX += fmaxf(e0 + c0.ff, 0.f);                                           \
    AY += fmaxf(e1 + c1.ff, 0.f);                                           \
  }

#define LOADATTR(R0, R1, R2, R3, R4, R5, R6, R7, JJ)                        \
  { const uint4* gp = cattr16 + (((size_t)(unsigned)(JJ)) << 1) + dz;       \
    R0 = gp[0]; R1 = gp[1]; R2 = gp[2]; R3 = gp[3];                         \
    R4 = gp[4]; R5 = gp[5]; R6 = gp[6]; R7 = gp[7]; }

#define GATH(D, S)                                                          \
  { const unsigned* rr = hb32 + ((size_t)(unsigned)(S)) * 64; D = rr[l]; }

  for (int n = wid; n < N; n += nw) {
    int jb = __builtin_amdgcn_readfirstlane(offs[n]);
    int je = __builtin_amdgcn_readfirstlane(offs[n + 1]);
    float ax = 0.f, ay = 0.f, bx = 0.f, by = 0.f;
    int j = jb;
    if (j + 8 <= je) {
      uint8v sc8 = sload8((const char*)csrc + ((size_t)(unsigned)j << 2));
      swait();
      for (;;) {
        unsigned ua0, ua1, ua2, ua3, ub0, ub1, ub2, ub3;
        uint4 Aa0, Aa1, Aa2, Aa3, Aa4, Aa5, Aa6, Aa7;
        uint4 Ab0, Ab1, Ab2, Ab3, Ab4, Ab5, Ab6, Ab7;
        GATH(ua0, sc8[0]) GATH(ua1, sc8[1]) GATH(ua2, sc8[2]) GATH(ua3, sc8[3])
        LOADATTR(Aa0, Aa1, Aa2, Aa3, Aa4, Aa5, Aa6, Aa7, j)
        GATH(ub0, sc8[4]) GATH(ub1, sc8[5]) GATH(ub2, sc8[6]) GATH(ub3, sc8[7])
        LOADATTR(Ab0, Ab1, Ab2, Ab3, Ab4, Ab5, Ab6, Ab7, j + 4)
        bool more = (j + 16 <= je);
        uint8v sc8n;
        if (more) sc8n = sload8((const char*)csrc + ((size_t)(unsigned)(j + 8) << 2));
        EDGE_V(Aa0, Aa1, ua0, ax, ay)
        EDGE_V(Aa2, Aa3, ua1, bx, by)
        EDGE_V(Aa4, Aa5, ua2, ax, ay)
        EDGE_V(Aa6, Aa7, ua3, bx, by)
        EDGE_V(Ab0, Ab1, ub0, ax, ay)
        EDGE_V(Ab2, Ab3, ub1, bx, by)
        EDGE_V(Ab4, Ab5, ub2, ax, ay)
        EDGE_V(Ab6, Ab7, ub3, bx, by)
        j += 8;
        if (!more) break;
        swait();                 // sc8n landed during the 8-edge compute
        sc8 = sc8n;
      }
    }
    if (j + 4 <= je) {
      uint4v sc4 = sload4((const char*)csrc + ((size_t)(unsigned)j << 2));
      swait();
      unsigned ua0, ua1, ua2, ua3;
      uint4 Aa0, Aa1, Aa2, Aa3, Aa4, Aa5, Aa6, Aa7;
      GATH(ua0, sc4[0]) GATH(ua1, sc4[1]) GATH(ua2, sc4[2]) GATH(ua3, sc4[3])
      LOADATTR(Aa0, Aa1, Aa2, Aa3, Aa4, Aa5, Aa6, Aa7, j)
      EDGE_V(Aa0, Aa1, ua0, ax, ay)
      EDGE_V(Aa2, Aa3, ua1, bx, by)
      EDGE_V(Aa4, Aa5, ua2, ax, ay)
      EDGE_V(Aa6, Aa7, ua3, bx, by)
      j += 4;
    }
    for (; j < je; ++j) {
      int s0 = csrc[j];
      unsigned u0 = hb_l[(size_t)s0 * 64];
      uint4 P0, P1;
      { const uint4* gp = cattr16 + (((size_t)(unsigned)j) << 1) + dz;
        P0 = gp[0]; P1 = gp[1]; }
      EDGE_V(P0, P1, u0, ax, ay)
    }
    float2 hvv = *(const float2*)(h + (size_t)n * 128 + 2 * l);
    float rx = hvv.x + ax + bx;
    float ry = hvv.y + ay + by;
    hpa16[(size_t)n * 64 + l] = ((unsigned)f2bf(ry) << 16) | (unsigned)f2bf(rx);
  }
#undef EDGE_V
#undef LOADATTR
#undef GATH
}

// ---------- MFMA node GEMM: hc = bf16(hpa) @ nn_W + nn_b, + fused BN stats ----------
// 128 rows/block, 4 waves x (2 row-tiles x 8 col-tiles) of 16x16x32 bf16 MFMA.
// A and WT (pre-transposed W, [n][k]) staged in LDS, rows padded +8 shorts
// (272 B stride -> 2-way bank aliasing, free). Stats: shfl-xor quad reduce ->
// LDS -> 256 atomics per block.
__global__ __launch_bounds__(256) void k_gemm_mfma(
    const unsigned short* __restrict__ A16, const unsigned short* __restrict__ WT16,
    const float* __restrict__ bias, float* __restrict__ hc,
    float* __restrict__ cstats, int N) {
  __shared__ short a_lds[128 * 136];
  __shared__ short w_lds[128 * 136];
  int t = threadIdx.x;
  int rowbase = blockIdx.x * 128;
  {
    int r = t >> 1;
    int off = (t & 1) * 64;              // shorts
    const short* ga = (const short*)A16 + (size_t)(rowbase + r) * 128 + off;
    short* la = &a_lds[r * 136 + off];
    const short* gw = (const short*)WT16 + (size_t)r * 128 + off;
    short* lw = &w_lds[r * 136 + off];
    if (rowbase + r < N) {
#pragma unroll
      for (int jj = 0; jj < 8; ++jj)
        *(uint4*)(la + jj * 8) = *(const uint4*)(ga + jj * 8);
    } else {
#pragma unroll
      for (int jj = 0; jj < 8; ++jj)
        *(uint4*)(la + jj * 8) = make_uint4(0, 0, 0, 0);
    }
#pragma unroll
    for (int jj = 0; jj < 8; ++jj)
      *(uint4*)(lw + jj * 8) = *(const uint4*)(gw + jj * 8);
  }
  __syncthreads();
  int w = t >> 6;
  int lane = t & 63;
  int l15 = lane & 15, quad = lane >> 4;
  f32x4 acc[2][8];
#pragma unroll
  for (int rt = 0; rt < 2; ++rt)
#pragma unroll
    for (int nt = 0; nt < 8; ++nt)
      acc[rt][nt] = (f32x4){0.f, 0.f, 0.f, 0.f};
#pragma unroll
  for (int kc = 0; kc < 4; ++kc) {
    int k0 = kc * 32 + quad * 8;
    short8 af0 = *(const short8*)&a_lds[(w * 32 + l15) * 136 + k0];
    short8 af1 = *(const short8*)&a_lds[(w * 32 + 16 + l15) * 136 + k0];
#pragma unroll
    for (int nt = 0; nt < 8; ++nt) {
      short8 bf = *(const short8*)&w_lds[(nt * 16 + l15) * 136 + k0];
      acc[0][nt] = __builtin_amdgcn_mfma_f32_16x16x32_bf16(af0, bf, acc[0][nt], 0, 0, 0);
      acc[1][nt] = __builtin_amdgcn_mfma_f32_16x16x32_bf16(af1, bf, acc[1][nt], 0, 0, 0);
    }
  }
  float sA[8], sQ[8];
#pragma unroll
  for (int nt = 0; nt < 8; ++nt) { sA[nt] = 0.f; sQ[nt] = 0.f; }
#pragma unroll
  for (int nt = 0; nt < 8; ++nt) {
    int col = nt * 16 + l15;
    float bv = bias[col];
#pragma unroll
    for (int rt = 0; rt < 2; ++rt) {
      int rbase = rowbase + w * 32 + rt * 16 + quad * 4;
#pragma unroll
      for (int reg = 0; reg < 4; ++reg) {
        int row = rbase + reg;
        float v = acc[rt][nt][reg] + bv;
        if (row < N) {
          hc[(size_t)row * 128 + col] = v;
          sA[nt] += v; sQ[nt] += v * v;
        }
      }
    }
  }
#pragma unroll
  for (int nt = 0; nt < 8; ++nt) {
    sA[nt] += __shfl_xor(sA[nt], 16);
    sA[nt] += __shfl_xor(sA[nt], 32);
    sQ[nt] += __shfl_xor(sQ[nt], 16);
    sQ[nt] += __shfl_xor(sQ[nt], 32);
  }
  __syncthreads();                    // done with a_lds/w_lds contents
  float* sdA = (float*)a_lds;         // [4][128]
  float* sdQ = (float*)w_lds;
  if (quad == 0) {
#pragma unroll
    for (int nt = 0; nt < 8; ++nt) {
      sdA[w * 128 + nt * 16 + l15] = sA[nt];
      sdQ[w * 128 + nt * 16 + l15] = sQ[nt];
    }
  }
  __syncthreads();
  if (t < 128) {
    float s = sdA[t] + sdA[128 + t] + sdA[256 + t] + sdA[384 + t];
    float s2 = sdQ[t] + sdQ[128 + t] + sdQ[256 + t] + sdQ[384 + t];
    atomicAdd(&cstats[t], s);
    atomicAdd(&cstats[128 + t], s2);
  }
}

// ---------- BN apply + exact GELU + residual: h += gelu(bn(hc)); bf16 shadow ----------
__global__ __launch_bounds__(256) void k_bn(const float* __restrict__ hc,
    const float* __restrict__ cstats,
    const float* __restrict__ g, const float* __restrict__ bb,
    float* __restrict__ h, unsigned short* __restrict__ hb, int N) {
  int idx = blockIdx.x * 256 + threadIdx.x;
  if (idx >= N * 32) return;
  int q = idx & 31;
  float invN = 1.f / (float)N;
  float4 cs = ((const float4*)cstats)[q];
  float4 cq = ((const float4*)cstats)[q + 32];
  float4 gv = ((const float4*)g)[q];
  float4 bv = ((const float4*)bb)[q];
  float4 v = ((const float4*)hc)[idx];
  float4 hv = ((const float4*)h)[idx];
#define BN1(X)                                                      \
  { float mu = cs.X * invN;                                         \
    float var = cq.X * invN - mu * mu;                              \
    float xn = (v.X - mu) * rsqrtf(var + 1e-5f) * gv.X + bv.X;      \
    hv.X += 0.5f * xn * (1.f + erff(xn * 0.70710678118654752f)); }
  BN1(x) BN1(y) BN1(z) BN1(w)
#undef BN1
  ((float4*)h)[idx] = hv;
  if (hb) {
    ushort4 hv4 = make_ushort4(f2bf(hv.x), f2bf(hv.y), f2bf(hv.z), f2bf(hv.w));
    *(ushort4*)(hb + (size_t)idx * 4) = hv4;
  }
}

// ---------- rep[g] = (sum over nodes of graph g of h[n]) @ lin_W + cnt*lin_b ----------
__global__ __launch_bounds__(256) void k_poolfinal(const float* __restrict__ h,
    const int* __restrict__ gstart, const float* __restrict__ W,
    const float* __restrict__ b, float* __restrict__ out) {
  int g = blockIdx.x;
  int t = threadIdx.x, c = t & 127, half = t >> 7;
  int n0 = gstart[g], n1 = gstart[g + 1];
  float s = 0.f;
  for (int n = n0 + half; n < n1; n += 2) s += h[(size_t)n * 128 + c];
  __shared__ float ls[256];
  __shared__ float pr[128];
  ls[t] = s; __syncthreads();
  if (t < 128) pr[t] = ls[t] + ls[t + 128];
  __syncthreads();
  float cnt = (float)(n1 - n0);
  float acc = cnt * b[t];
#pragma unroll 8
  for (int k = 0; k < 128; ++k) acc += pr[k] * W[(size_t)k * 256 + t];
  out[(size_t)g * 256 + t] = acc;
}

extern "C" void kernel_launch(void* const* d_in, const int* in_sizes, int n_in,
                              void* d_out, int out_size, void* d_ws, size_t ws_size,
                              hipStream_t stream) {
  const float* x     = (const float*)d_in[0];
  const int*   eidx  = (const int*)d_in[1];
  const float* eattr = (const float*)d_in[2];
  const int*   batch = (const int*)d_in[3];
  const float* embW  = (const float*)d_in[4];
  const float* embB  = (const float*)d_in[5];
  const float* edgeW = (const float*)d_in[6];
  const float* edgeB = (const float*)d_in[7];
  const float* nnW   = (const float*)d_in[8];
  const float* nnB   = (const float*)d_in[9];
  const float* bnG   = (const float*)d_in[10];
  const float* bnB   = (const float*)d_in[11];
  const float* linW  = (const float*)d_in[12];
  const float* linB  = (const float*)d_in[13];
  float* out = (float*)d_out;

  int N = in_sizes[0] / 8;
  int E = in_sizes[1] / 2;
  const int* src = eidx;
  const int* dst = eidx + E;

  // workspace carve-up (~220 MB); attr16c aliases hc, perm aliases hpa16
  char* wptr = (char*)d_ws;
  auto alloc = [&](size_t bytes) {
    char* p = wptr; wptr += (bytes + 255) & ~(size_t)255; return p;
  };
  size_t hc_bytes = (size_t)N * 128 * 4;
  if ((size_t)E * 32 > hc_bytes) hc_bytes = (size_t)E * 32;
  size_t hpa_bytes = (size_t)N * 64 * 4;
  if ((size_t)E * 4 > hpa_bytes) hpa_bytes = (size_t)E * 4;
  float* h      = (float*)alloc((size_t)N * 128 * 4);
  float* hc     = (float*)alloc(hc_bytes);              // fp32 GEMM output
  unsigned short* hb = (unsigned short*)alloc((size_t)N * 128 * 2);  // bf16 h shadow
  unsigned* hpa16 = (unsigned*)alloc(hpa_bytes);        // bf16 h+agg (GEMM input)
  uint4* cattr16 = (uint4*)alloc((size_t)E * 32);       // fp16 attrs, 32 B/edge
  int*   csrc   = (int*)alloc((size_t)E * 4);
  int*   offs   = (int*)alloc((size_t)(N + 1) * 4);
  int*   cursor = (int*)alloc((size_t)N * 4);
  int*   deg    = (int*)alloc((size_t)N * 4);
  int nb = (N + 255) / 256;
  int*   bsum   = (int*)alloc((size_t)nb * 4);
  float* cstats = (float*)alloc(256 * 4);               // colsum | colsumsq
  unsigned* eW16 = (unsigned*)alloc(4096 * 4);          // [4][8][128] packed half2 pairs
  unsigned short* WT16 = (unsigned short*)alloc(4 * 128 * 128 * 2);  // bf16 W^T
  int*   gstart = (int*)alloc((size_t)(GG + 1) * 4);

  uint4* attr16c = (uint4*)hc;     // alias: dead before first GEMM
  int*   perm    = (int*)hpa16;    // alias: dead before first edge_agg

  int q32 = (N * 32 + 255) / 256;

  hipMemsetAsync(deg, 0, (size_t)N * 4, stream);
  k_emb<<<q32, 256, 0, stream>>>(x, embW, embB, h, hb, N);
  k_wconv<<<16, 256, 0, stream>>>(edgeW, eW16);
  k_nnconv<<<256, 256, 0, stream>>>(nnW, WT16);
  k_aconv<<<(E * 2 + 255) / 256, 256, 0, stream>>>(eattr, attr16c, E * 2);
  k_hist<<<(E + 255) / 256, 256, 0, stream>>>(dst, deg, E);
  k_scan_reduce<<<nb, 256, 0, stream>>>(deg, bsum, N);
  k_scan_mid<<<1, 512, 0, stream>>>(bsum, nb);
  k_scan_final<<<nb, 256, 0, stream>>>(deg, bsum, offs, cursor, N);
  k_fillperm<<<(E + 255) / 256, 256, 0, stream>>>(src, dst, cursor, csrc, perm, E);
  k_permgather<<<(E + 255) / 256, 256, 0, stream>>>(perm, attr16c, cattr16, E);
  k_gstart<<<(N + 255) / 256, 256, 0, stream>>>(batch, gstart, N, GG);

  int gblk = (N + 127) / 128;
  for (int l = 0; l < 4; ++l) {
    k_edge_agg<<<8192, 256, 0, stream>>>(h, (const unsigned*)hb, cattr16, csrc,
        offs, eW16 + (size_t)l * 1024, edgeB + (size_t)l * 128, hpa16, cstats, N);
    k_gemm_mfma<<<gblk, 256, 0, stream>>>((const unsigned short*)hpa16,
        WT16 + (size_t)l * 128 * 128, nnB + (size_t)l * 128, hc, cstats, N);
    k_bn<<<q32, 256, 0, stream>>>(hc, cstats,
        bnG + (size_t)l * 128, bnB + (size_t)l * 128, h, (l == 3) ? nullptr : hb, N);
  }
  k_poolfinal<<<GG, 256, 0, stream>>>(h, gstart, linW, linB, out);
}

// Round 5
// 1087.067 us; speedup vs baseline: 1.2336x; 1.2336x over previous
//
#include <hip/hip_runtime.h>
#include <hip/hip_fp16.h>
#include <math.h>

// Problem constants (from reference): N=100000, E=1600000, F_IN=8, H=128,
// L=4, E_FEAT=16, G=256, OUT=256. N/E derived from in_sizes at launch.
#define GG 256

typedef __attribute__((ext_vector_type(8))) short short8;
typedef __attribute__((ext_vector_type(4))) float f32x4;
typedef _Float16 half2v __attribute__((ext_vector_type(2)));
typedef __attribute__((ext_vector_type(4))) unsigned uint4v;

__device__ __forceinline__ unsigned short f2bf(float x) {
  union { float f; unsigned u; } v; v.f = x;
  unsigned r = v.u + 0x7fff + ((v.u >> 16) & 1);   // round-to-nearest-even
  return (unsigned short)(r >> 16);
}

__device__ __forceinline__ unsigned pack_h2(float a, float b) {
  __half2 h = __floats2half2_rn(a, b);
  return *(unsigned*)&h;
}

// v_dot2_f32_f16: D = a.lo*b.lo + a.hi*b.hi + c  (f32 accumulate)
__device__ __forceinline__ float fdot2u(unsigned a, unsigned b, float c) {
  half2v av, bv;
  __builtin_memcpy(&av, &a, 4);
  __builtin_memcpy(&bv, &b, 4);
  return __builtin_amdgcn_fdot2(av, bv, c, false);
}

// scalar load (wave-uniform address) — SMEM path, SALU addressing
__device__ __forceinline__ uint4v sload4(const void* p) {
  uint4v r;
  asm volatile("s_load_dwordx4 %0, %1, 0x0"
               : "=s"(r) : "s"((unsigned long long)p));
  return r;
}
__device__ __forceinline__ void swait() {
  asm volatile("s_waitcnt lgkmcnt(0)" ::: "memory");
  __builtin_amdgcn_sched_barrier(0);   // rule #18: pin consumers after the wait
}

// ---------- h = x @ emb_W + emb_b  ([N,8]@[8,128]); also writes bf16 shadow ----------
__global__ __launch_bounds__(256) void k_emb(const float* __restrict__ x,
    const float* __restrict__ W, const float* __restrict__ b,
    float* __restrict__ h, unsigned short* __restrict__ hb, int N) {
  int idx = blockIdx.x * 256 + threadIdx.x;      // one float4 of output per thread
  if (idx >= N * 32) return;
  int n = idx >> 5, q = idx & 31;
  const float* xr = x + (size_t)n * 8;
  float xs[8];
#pragma unroll
  for (int k = 0; k < 8; ++k) xs[k] = xr[k];
  float4 acc = ((const float4*)b)[q];
#pragma unroll
  for (int k = 0; k < 8; ++k) {
    float4 w = ((const float4*)(W + (size_t)k * 128))[q];
    acc.x += xs[k] * w.x; acc.y += xs[k] * w.y;
    acc.z += xs[k] * w.z; acc.w += xs[k] * w.w;
  }
  ((float4*)h)[idx] = acc;
  ushort4 hv4 = make_ushort4(f2bf(acc.x), f2bf(acc.y), f2bf(acc.z), f2bf(acc.w));
  *(ushort4*)(hb + (size_t)idx * 4) = hv4;
}

// ---------- edge weights -> packed fp16 PAIRS along k (dot2 layout) ----------
// eWp[l][k][c] = half2( W[l][2k][c], W[l][2k+1][c] ),  k=0..7, c=0..127
__global__ __launch_bounds__(256) void k_wconv(const float* __restrict__ eW,
    unsigned* __restrict__ eWp) {              // 4*8*128 = 4096 pairs
  int i = blockIdx.x * 256 + threadIdx.x;
  if (i >= 4096) return;
  int c = i & 127, k = (i >> 7) & 7, l = i >> 10;
  const float* base = eW + ((size_t)(l * 16 + 2 * k) * 128 + c);
  eWp[i] = pack_h2(base[0], base[128]);
}

// ---------- transpose nn_W to bf16: WT[l][n][k] = bf16(nn_W[l][k][n]) ----------
__global__ __launch_bounds__(256) void k_nnconv(const float* __restrict__ W,
    unsigned short* __restrict__ WT) {
  int i = blockIdx.x * 256 + threadIdx.x;    // i = ((l*128)+k)*128 + n
  if (i >= 4 * 128 * 128) return;
  int n = i & 127, k = (i >> 7) & 127, l = i >> 14;
  WT[((size_t)(l * 128 + n)) * 128 + k] = f2bf(W[i]);
}

// ---------- CSR build ----------
__global__ void k_hist(const int* __restrict__ dst, int* __restrict__ deg, int E) {
  int e = blockIdx.x * blockDim.x + threadIdx.x;
  if (e < E) atomicAdd(&deg[dst[e]], 1);
}

__global__ __launch_bounds__(256) void k_scan_reduce(const int* __restrict__ deg,
    int* __restrict__ bsum, int N) {
  __shared__ int sd[256];
  int i = blockIdx.x * 256 + threadIdx.x;
  sd[threadIdx.x] = (i < N) ? deg[i] : 0;
  __syncthreads();
  for (int s = 128; s > 0; s >>= 1) {
    if (threadIdx.x < s) sd[threadIdx.x] += sd[threadIdx.x + s];
    __syncthreads();
  }
  if (threadIdx.x == 0) bsum[blockIdx.x] = sd[0];
}

// single-block exclusive scan over nb (<=512) block sums
__global__ __launch_bounds__(512) void k_scan_mid(int* bsum, int nb) {
  __shared__ int sd[512];
  int t = threadIdx.x;
  int v = (t < nb) ? bsum[t] : 0;
  sd[t] = v; __syncthreads();
  for (int d = 1; d < 512; d <<= 1) {
    int xv = (t >= d) ? sd[t - d] : 0;
    __syncthreads();
    sd[t] += xv;
    __syncthreads();
  }
  if (t < nb) bsum[t] = sd[t] - v;   // exclusive
}

__global__ __launch_bounds__(256) void k_scan_final(const int* __restrict__ deg,
    const int* __restrict__ bsum, int* __restrict__ offs,
    int* __restrict__ cursor, int N) {
  __shared__ int sd[256];
  int t = threadIdx.x;
  int i = blockIdx.x * 256 + t;
  int v = (i < N) ? deg[i] : 0;
  sd[t] = v; __syncthreads();
  for (int d = 1; d < 256; d <<= 1) {           // Hillis-Steele inclusive scan
    int xv = (t >= d) ? sd[t - d] : 0;
    __syncthreads();
    sd[t] += xv;
    __syncthreads();
  }
  int off = bsum[blockIdx.x] + sd[t] - v;       // exclusive
  if (i < N) {
    offs[i] = off; cursor[i] = off;
    if (i == N - 1) offs[N] = off + v;
  }
}

// fill CSR: permute src + attr (converted to fp16, 32 B/edge) into dst order
__global__ void k_fill(const int* __restrict__ src, const int* __restrict__ dst,
    const float* __restrict__ attr, int* __restrict__ cursor,
    int* __restrict__ csrc, uint4* __restrict__ cattr16, int E) {
  int e = blockIdx.x * blockDim.x + threadIdx.x;
  if (e >= E) return;
  int d = dst[e];
  int pos = atomicAdd(&cursor[d], 1);
  csrc[pos] = src[e];
  const float4* a = (const float4*)(attr + (size_t)e * 16);
  float4 a0 = a[0], a1 = a[1], a2 = a[2], a3 = a[3];
  uint4 o0, o1;
  o0.x = pack_h2(a0.x, a0.y); o0.y = pack_h2(a0.z, a0.w);
  o0.z = pack_h2(a1.x, a1.y); o0.w = pack_h2(a1.z, a1.w);
  o1.x = pack_h2(a2.x, a2.y); o1.y = pack_h2(a2.z, a2.w);
  o1.z = pack_h2(a3.x, a3.y); o1.w = pack_h2(a3.z, a3.w);
  cattr16[(size_t)pos * 2] = o0;
  cattr16[(size_t)pos * 2 + 1] = o1;
}

// ---------- graph boundaries (batch is sorted) ----------
__global__ void k_gstart(const int* __restrict__ batch, int* __restrict__ gstart,
                         int N, int Gn) {
  int i = blockIdx.x * blockDim.x + threadIdx.x;
  if (i >= N) return;
  int b = batch[i];
  if (i == 0) { for (int g = 0; g <= b; ++g) gstart[g] = 0; }
  else { int bp = batch[i - 1]; for (int g = bp + 1; g <= b; ++g) gstart[g] = i; }
  if (i == N - 1) { for (int g = b + 1; g <= Gn; ++g) gstart[g] = N; }
}

// ---------- fused edge embed + gather + relu + aggregate (v5: SMEM ping-pong) ----------
// hpa16[n] = bf16( h[n] + sum_j relu( attr[j]@edge_W + edge_b + h[src[j]] ) )
// Wave-stride over nodes. Lane owns cols 2l,2l+1.
// Per 4-edge group: csrc+attrs live in SGPRs (9x s_load_dwordx4). Ping-pong
// A/B register sets: group k+1's s_loads are issued after group k's gathers
// and BEFORE group k's compute, so SMEM latency hides under 64 fdot2s.
// Gathers (vmcnt) and SMEM (lgkmcnt) overlap on separate counters.
__global__ __launch_bounds__(256) void k_edge_agg(const float* __restrict__ h,
    const unsigned* __restrict__ hb32,       // bf16 shadow viewed as uint
    const uint4* __restrict__ cattr16, const int* __restrict__ csrc,
    const int* __restrict__ offs, const unsigned* __restrict__ eWp,
    const float* __restrict__ eb, unsigned* __restrict__ hpa16,
    float* __restrict__ cstats, int N) {
  int t = threadIdx.x;
  if (blockIdx.x == 0) cstats[t] = 0.f;    // 256 floats: colsum|colsumsq
  int l = t & 63;                           // lane -> columns 2l, 2l+1
  int wid = blockIdx.x * 4 + (t >> 6);
  int nw = gridDim.x * 4;
  uint2 wp[8];                              // wp[k].x pairs for col 2l, .y for 2l+1
#pragma unroll
  for (int k = 0; k < 8; ++k) wp[k] = *(const uint2*)&eWp[k * 128 + 2 * l];
  float2 bias = *(const float2*)(eb + 2 * l);
  const unsigned* hb_l = hb32 + l;          // + s*64 per edge (row = 64 uints)

// one edge: attrs in two uint4v SGPR quads P,Q; gathered bf16 pair UU
#define EDGE_SG(P, Q, UU, AX, AY)                                           \
  {                                                                         \
    float e0 = bias.x, e1 = bias.y;                                         \
    e0 = fdot2u(P[0], wp[0].x, e0); e1 = fdot2u(P[0], wp[0].y, e1);         \
    e0 = fdot2u(P[1], wp[1].x, e0); e1 = fdot2u(P[1], wp[1].y, e1);         \
    e0 = fdot2u(P[2], wp[2].x, e0); e1 = fdot2u(P[2], wp[2].y, e1);         \
    e0 = fdot2u(P[3], wp[3].x, e0); e1 = fdot2u(P[3], wp[3].y, e1);         \
    e0 = fdot2u(Q[0], wp[4].x, e0); e1 = fdot2u(Q[0], wp[4].y, e1);         \
    e0 = fdot2u(Q[1], wp[5].x, e0); e1 = fdot2u(Q[1], wp[5].y, e1);         \
    e0 = fdot2u(Q[2], wp[6].x, e0); e1 = fdot2u(Q[2], wp[6].y, e1);         \
    e0 = fdot2u(Q[3], wp[7].x, e0); e1 = fdot2u(Q[3], wp[7].y, e1);         \
    union { unsigned uu; float ff; } c0, c1;                                \
    c0.uu = (UU) << 16; c1.uu = (UU) & 0xffff0000u;                         \
    AX += fmaxf(e0 + c0.ff, 0.f);                                           \
    AY += fmaxf(e1 + c1.ff, 0.f);                                           \
  }

// plain-VMEM fallback for remainder edges
#define EDGE2(JJ, UU, AX, AY)                                               \
  {                                                                         \
    uint4 q0 = cattr16[(size_t)(JJ) * 2];                                   \
    uint4 q1 = cattr16[(size_t)(JJ) * 2 + 1];                               \
    float e0 = bias.x, e1 = bias.y;                                         \
    e0 = fdot2u(q0.x, wp[0].x, e0); e1 = fdot2u(q0.x, wp[0].y, e1);         \
    e0 = fdot2u(q0.y, wp[1].x, e0); e1 = fdot2u(q0.y, wp[1].y, e1);         \
    e0 = fdot2u(q0.z, wp[2].x, e0); e1 = fdot2u(q0.z, wp[2].y, e1);         \
    e0 = fdot2u(q0.w, wp[3].x, e0); e1 = fdot2u(q0.w, wp[3].y, e1);         \
    e0 = fdot2u(q1.x, wp[4].x, e0); e1 = fdot2u(q1.x, wp[4].y, e1);         \
    e0 = fdot2u(q1.y, wp[5].x, e0); e1 = fdot2u(q1.y, wp[5].y, e1);         \
    e0 = fdot2u(q1.z, wp[6].x, e0); e1 = fdot2u(q1.z, wp[6].y, e1);         \
    e0 = fdot2u(q1.w, wp[7].x, e0); e1 = fdot2u(q1.w, wp[7].y, e1);         \
    union { unsigned uu; float ff; } c0, c1;                                \
    c0.uu = (UU) << 16; c1.uu = (UU) & 0xffff0000u;                         \
    AX += fmaxf(e0 + c0.ff, 0.f);                                           \
    AY += fmaxf(e1 + c1.ff, 0.f);                                           \
  }

// issue the 9 s_loads for a 4-edge group at edge index JJ into register set S
#define LOADGRP(SC, A0, A1, A2, A3, A4, A5, A6, A7, JJ)                     \
  { const char* ab_ = (const char*)cattr16 + ((size_t)(unsigned)(JJ) << 5); \
    SC = sload4((const char*)csrc + ((size_t)(unsigned)(JJ) << 2));         \
    A0 = sload4(ab_);       A1 = sload4(ab_ + 16);                          \
    A2 = sload4(ab_ + 32);  A3 = sload4(ab_ + 48);                          \
    A4 = sload4(ab_ + 64);  A5 = sload4(ab_ + 80);                          \
    A6 = sload4(ab_ + 96);  A7 = sload4(ab_ + 112); }

#define GATH4(SC, U0, U1, U2, U3)                                           \
  { U0 = hb_l[(size_t)(SC[0]) * 64]; U1 = hb_l[(size_t)(SC[1]) * 64];       \
    U2 = hb_l[(size_t)(SC[2]) * 64]; U3 = hb_l[(size_t)(SC[3]) * 64]; }

  for (int n = wid; n < N; n += nw) {
    int jb = __builtin_amdgcn_readfirstlane(offs[n]);
    int je = __builtin_amdgcn_readfirstlane(offs[n + 1]);
    float ax = 0.f, ay = 0.f, bx = 0.f, by = 0.f;
    int j = jb;
    if (j + 4 <= je) {
      uint4v scA, pA0, pA1, pA2, pA3, pA4, pA5, pA6, pA7;
      uint4v scB, pB0, pB1, pB2, pB3, pB4, pB5, pB6, pB7;
      LOADGRP(scA, pA0, pA1, pA2, pA3, pA4, pA5, pA6, pA7, j)
      swait();
      for (;;) {
        {  // process A, prefetch into B
          unsigned u0, u1, u2, u3;
          GATH4(scA, u0, u1, u2, u3)
          bool more = (j + 8 <= je);
          if (more) LOADGRP(scB, pB0, pB1, pB2, pB3, pB4, pB5, pB6, pB7, j + 4)
          EDGE_SG(pA0, pA1, u0, ax, ay)
          EDGE_SG(pA2, pA3, u1, bx, by)
          EDGE_SG(pA4, pA5, u2, ax, ay)
          EDGE_SG(pA6, pA7, u3, bx, by)
          j += 4;
          if (!more) break;
          swait();
        }
        {  // process B, prefetch into A
          unsigned u0, u1, u2, u3;
          GATH4(scB, u0, u1, u2, u3)
          bool more = (j + 8 <= je);
          if (more) LOADGRP(scA, pA0, pA1, pA2, pA3, pA4, pA5, pA6, pA7, j + 4)
          EDGE_SG(pB0, pB1, u0, ax, ay)
          EDGE_SG(pB2, pB3, u1, bx, by)
          EDGE_SG(pB4, pB5, u2, ax, ay)
          EDGE_SG(pB6, pB7, u3, bx, by)
          j += 4;
          if (!more) break;
          swait();
        }
      }
    }
    for (; j < je; ++j) {
      int s0 = csrc[j];
      unsigned u0 = hb_l[(size_t)s0 * 64];
      EDGE2(j, u0, ax, ay)
    }
    float2 hvv = *(const float2*)(h + (size_t)n * 128 + 2 * l);
    float rx = hvv.x + ax + bx;
    float ry = hvv.y + ay + by;
    hpa16[(size_t)n * 64 + l] = ((unsigned)f2bf(ry) << 16) | (unsigned)f2bf(rx);
  }
#undef EDGE_SG
#undef EDGE2
#undef LOADGRP
#undef GATH4
}

// ---------- MFMA node GEMM: hc = bf16(hpa) @ nn_W + nn_b, + fused BN stats ----------
// 128 rows/block, 4 waves x (2 row-tiles x 8 col-tiles) of 16x16x32 bf16 MFMA.
// A and WT (pre-transposed W, [n][k]) staged in LDS, rows padded +8 shorts
// (272 B stride -> 2-way bank aliasing, free). Stats: shfl-xor quad reduce ->
// LDS -> 256 atomics per block.
__global__ __launch_bounds__(256) void k_gemm_mfma(
    const unsigned short* __restrict__ A16, const unsigned short* __restrict__ WT16,
    const float* __restrict__ bias, float* __restrict__ hc,
    float* __restrict__ cstats, int N) {
  __shared__ short a_lds[128 * 136];
  __shared__ short w_lds[128 * 136];
  int t = threadIdx.x;
  int rowbase = blockIdx.x * 128;
  {
    int r = t >> 1;
    int off = (t & 1) * 64;              // shorts
    const short* ga = (const short*)A16 + (size_t)(rowbase + r) * 128 + off;
    short* la = &a_lds[r * 136 + off];
    const short* gw = (const short*)WT16 + (size_t)r * 128 + off;
    short* lw = &w_lds[r * 136 + off];
    if (rowbase + r < N) {
#pragma unroll
      for (int jj = 0; jj < 8; ++jj)
        *(uint4*)(la + jj * 8) = *(const uint4*)(ga + jj * 8);
    } else {
#pragma unroll
      for (int jj = 0; jj < 8; ++jj)
        *(uint4*)(la + jj * 8) = make_uint4(0, 0, 0, 0);
    }
#pragma unroll
    for (int jj = 0; jj < 8; ++jj)
      *(uint4*)(lw + jj * 8) = *(const uint4*)(gw + jj * 8);
  }
  __syncthreads();
  int w = t >> 6;
  int lane = t & 63;
  int l15 = lane & 15, quad = lane >> 4;
  f32x4 acc[2][8];
#pragma unroll
  for (int rt = 0; rt < 2; ++rt)
#pragma unroll
    for (int nt = 0; nt < 8; ++nt)
      acc[rt][nt] = (f32x4){0.f, 0.f, 0.f, 0.f};
#pragma unroll
  for (int kc = 0; kc < 4; ++kc) {
    int k0 = kc * 32 + quad * 8;
    short8 af0 = *(const short8*)&a_lds[(w * 32 + l15) * 136 + k0];
    short8 af1 = *(const short8*)&a_lds[(w * 32 + 16 + l15) * 136 + k0];
#pragma unroll
    for (int nt = 0; nt < 8; ++nt) {
      short8 bf = *(const short8*)&w_lds[(nt * 16 + l15) * 136 + k0];
      acc[0][nt] = __builtin_amdgcn_mfma_f32_16x16x32_bf16(af0, bf, acc[0][nt], 0, 0, 0);
      acc[1][nt] = __builtin_amdgcn_mfma_f32_16x16x32_bf16(af1, bf, acc[1][nt], 0, 0, 0);
    }
  }
  float sA[8], sQ[8];
#pragma unroll
  for (int nt = 0; nt < 8; ++nt) { sA[nt] = 0.f; sQ[nt] = 0.f; }
#pragma unroll
  for (int nt = 0; nt < 8; ++nt) {
    int col = nt * 16 + l15;
    float bv = bias[col];
#pragma unroll
    for (int rt = 0; rt < 2; ++rt) {
      int rbase = rowbase + w * 32 + rt * 16 + quad * 4;
#pragma unroll
      for (int reg = 0; reg < 4; ++reg) {
        int row = rbase + reg;
        float v = acc[rt][nt][reg] + bv;
        if (row < N) {
          hc[(size_t)row * 128 + col] = v;
          sA[nt] += v; sQ[nt] += v * v;
        }
      }
    }
  }
#pragma unroll
  for (int nt = 0; nt < 8; ++nt) {
    sA[nt] += __shfl_xor(sA[nt], 16);
    sA[nt] += __shfl_xor(sA[nt], 32);
    sQ[nt] += __shfl_xor(sQ[nt], 16);
    sQ[nt] += __shfl_xor(sQ[nt], 32);
  }
  __syncthreads();                    // done with a_lds/w_lds contents
  float* sdA = (float*)a_lds;         // [4][128]
  float* sdQ = (float*)w_lds;
  if (quad == 0) {
#pragma unroll
    for (int nt = 0; nt < 8; ++nt) {
      sdA[w * 128 + nt * 16 + l15] = sA[nt];
      sdQ[w * 128 + nt * 16 + l15] = sQ[nt];
    }
  }
  __syncthreads();
  if (t < 128) {
    float s = sdA[t] + sdA[128 + t] + sdA[256 + t] + sdA[384 + t];
    float s2 = sdQ[t] + sdQ[128 + t] + sdQ[256 + t] + sdQ[384 + t];
    atomicAdd(&cstats[t], s);
    atomicAdd(&cstats[128 + t], s2);
  }
}

// ---------- BN apply + exact GELU + residual: h += gelu(bn(hc)); bf16 shadow ----------
__global__ __launch_bounds__(256) void k_bn(const float* __restrict__ hc,
    const float* __restrict__ cstats,
    const float* __restrict__ g, const float* __restrict__ bb,
    float* __restrict__ h, unsigned short* __restrict__ hb, int N) {
  int idx = blockIdx.x * 256 + threadIdx.x;
  if (idx >= N * 32) return;
  int q = idx & 31;
  float invN = 1.f / (float)N;
  float4 cs = ((const float4*)cstats)[q];
  float4 cq = ((const float4*)cstats)[q + 32];
  float4 gv = ((const float4*)g)[q];
  float4 bv = ((const float4*)bb)[q];
  float4 v = ((const float4*)hc)[idx];
  float4 hv = ((const float4*)h)[idx];
#define BN1(X)                                                      \
  { float mu = cs.X * invN;                                         \
    float var = cq.X * invN - mu * mu;                              \
    float xn = (v.X - mu) * rsqrtf(var + 1e-5f) * gv.X + bv.X;      \
    hv.X += 0.5f * xn * (1.f + erff(xn * 0.70710678118654752f)); }
  BN1(x) BN1(y) BN1(z) BN1(w)
#undef BN1
  ((float4*)h)[idx] = hv;
  if (hb) {
    ushort4 hv4 = make_ushort4(f2bf(hv.x), f2bf(hv.y), f2bf(hv.z), f2bf(hv.w));
    *(ushort4*)(hb + (size_t)idx * 4) = hv4;
  }
}

// ---------- rep[g] = (sum over nodes of graph g of h[n]) @ lin_W + cnt*lin_b ----------
__global__ __launch_bounds__(256) void k_poolfinal(const float* __restrict__ h,
    const int* __restrict__ gstart, const float* __restrict__ W,
    const float* __restrict__ b, float* __restrict__ out) {
  int g = blockIdx.x;
  int t = threadIdx.x, c = t & 127, half = t >> 7;
  int n0 = gstart[g], n1 = gstart[g + 1];
  float s = 0.f;
  for (int n = n0 + half; n < n1; n += 2) s += h[(size_t)n * 128 + c];
  __shared__ float ls[256];
  __shared__ float pr[128];
  ls[t] = s; __syncthreads();
  if (t < 128) pr[t] = ls[t] + ls[t + 128];
  __syncthreads();
  float cnt = (float)(n1 - n0);
  float acc = cnt * b[t];
#pragma unroll 8
  for (int k = 0; k < 128; ++k) acc += pr[k] * W[(size_t)k * 256 + t];
  out[(size_t)g * 256 + t] = acc;
}

extern "C" void kernel_launch(void* const* d_in, const int* in_sizes, int n_in,
                              void* d_out, int out_size, void* d_ws, size_t ws_size,
                              hipStream_t stream) {
  const float* x     = (const float*)d_in[0];
  const int*   eidx  = (const int*)d_in[1];
  const float* eattr = (const float*)d_in[2];
  const int*   batch = (const int*)d_in[3];
  const float* embW  = (const float*)d_in[4];
  const float* embB  = (const float*)d_in[5];
  const float* edgeW = (const float*)d_in[6];
  const float* edgeB = (const float*)d_in[7];
  const float* nnW   = (const float*)d_in[8];
  const float* nnB   = (const float*)d_in[9];
  const float* bnG   = (const float*)d_in[10];
  const float* bnB   = (const float*)d_in[11];
  const float* linW  = (const float*)d_in[12];
  const float* linB  = (const float*)d_in[13];
  float* out = (float*)d_out;

  int N = in_sizes[0] / 8;
  int E = in_sizes[1] / 2;
  const int* src = eidx;
  const int* dst = eidx + E;

  // workspace carve-up (~220 MB)
  char* wptr = (char*)d_ws;
  auto alloc = [&](size_t bytes) {
    char* p = wptr; wptr += (bytes + 255) & ~(size_t)255; return p;
  };
  float* h      = (float*)alloc((size_t)N * 128 * 4);
  float* hc     = (float*)alloc((size_t)N * 128 * 4);   // fp32 GEMM output
  unsigned short* hb = (unsigned short*)alloc((size_t)N * 128 * 2);  // bf16 h shadow
  unsigned* hpa16 = (unsigned*)alloc((size_t)N * 64 * 4);  // bf16 h+agg (GEMM input)
  uint4* cattr16 = (uint4*)alloc((size_t)E * 32);       // fp16 attrs, 32 B/edge
  int*   csrc   = (int*)alloc((size_t)E * 4);
  int*   offs   = (int*)alloc((size_t)(N + 1) * 4);
  int*   cursor = (int*)alloc((size_t)N * 4);
  int*   deg    = (int*)alloc((size_t)N * 4);
  int nb = (N + 255) / 256;
  int*   bsum   = (int*)alloc((size_t)nb * 4);
  float* cstats = (float*)alloc(256 * 4);               // colsum | colsumsq
  unsigned* eW16 = (unsigned*)alloc(4096 * 4);          // [4][8][128] packed half2 pairs
  unsigned short* WT16 = (unsigned short*)alloc(4 * 128 * 128 * 2);  // bf16 W^T
  int*   gstart = (int*)alloc((size_t)(GG + 1) * 4);

  int q32 = (N * 32 + 255) / 256;

  hipMemsetAsync(deg, 0, (size_t)N * 4, stream);
  k_emb<<<q32, 256, 0, stream>>>(x, embW, embB, h, hb, N);
  k_wconv<<<16, 256, 0, stream>>>(edgeW, eW16);
  k_nnconv<<<256, 256, 0, stream>>>(nnW, WT16);
  k_hist<<<(E + 255) / 256, 256, 0, stream>>>(dst, deg, E);
  k_scan_reduce<<<nb, 256, 0, stream>>>(deg, bsum, N);
  k_scan_mid<<<1, 512, 0, stream>>>(bsum, nb);
  k_scan_final<<<nb, 256, 0, stream>>>(deg, bsum, offs, cursor, N);
  k_fill<<<(E + 255) / 256, 256, 0, stream>>>(src, dst, eattr, cursor, csrc, cattr16, E);
  k_gstart<<<(N + 255) / 256, 256, 0, stream>>>(batch, gstart, N, GG);

  int gblk = (N + 127) / 128;
  for (int l = 0; l < 4; ++l) {
    k_edge_agg<<<8192, 256, 0, stream>>>(h, (const unsigned*)hb, cattr16, csrc,
        offs, eW16 + (size_t)l * 1024, edgeB + (size_t)l * 128, hpa16, cstats, N);
    k_gemm_mfma<<<gblk, 256, 0, stream>>>((const unsigned short*)hpa16,
        WT16 + (size_t)l * 128 * 128, nnB + (size_t)l * 128, hc, cstats, N);
    k_bn<<<q32, 256, 0, stream>>>(hc, cstats,
        bnG + (size_t)l * 128, bnB + (size_t)l * 128, h, (l == 3) ? nullptr : hb, N);
  }
  k_poolfinal<<<GG, 256, 0, stream>>>(h, gstart, linW, linB, out);
}

// Round 6
// 1064.007 us; speedup vs baseline: 1.2603x; 1.0217x over previous
//
#include <hip/hip_runtime.h>
#include <hip/hip_fp16.h>
#include <math.h>

// Problem constants (from reference): N=100000, E=1600000, F_IN=8, H=128,
// L=4, E_FEAT=16, G=256, OUT=256. N/E derived from in_sizes at launch.
#define GG 256

typedef __attribute__((ext_vector_type(8))) short short8;
typedef __attribute__((ext_vector_type(4))) float f32x4;
typedef _Float16 half4v __attribute__((ext_vector_type(4)));
typedef __attribute__((ext_vector_type(8))) unsigned uint8v;

__device__ __forceinline__ unsigned short f2bf(float x) {
  union { float f; unsigned u; } v; v.f = x;
  unsigned r = v.u + 0x7fff + ((v.u >> 16) & 1);   // round-to-nearest-even
  return (unsigned short)(r >> 16);
}

__device__ __forceinline__ unsigned pack_h2(float a, float b) {
  __half2 h = __floats2half2_rn(a, b);
  return *(unsigned*)&h;
}

// scalar load (wave-uniform address) — SMEM path, SALU addressing
__device__ __forceinline__ uint8v sload8(const void* p) {
  uint8v r;
  asm volatile("s_load_dwordx8 %0, %1, 0x0"
               : "=s"(r) : "s"((unsigned long long)p));
  return r;
}
__device__ __forceinline__ void swait() {
  asm volatile("s_waitcnt lgkmcnt(0)" ::: "memory");
  __builtin_amdgcn_sched_barrier(0);   // rule #18: pin consumers after the wait
}

// ---------- h = x @ emb_W + emb_b  ([N,8]@[8,128]); also writes bf16 shadow ----------
__global__ __launch_bounds__(256) void k_emb(const float* __restrict__ x,
    const float* __restrict__ W, const float* __restrict__ b,
    float* __restrict__ h, unsigned short* __restrict__ hb, int N) {
  int idx = blockIdx.x * 256 + threadIdx.x;      // one float4 of output per thread
  if (idx >= N * 32) return;
  int n = idx >> 5, q = idx & 31;
  const float* xr = x + (size_t)n * 8;
  float xs[8];
#pragma unroll
  for (int k = 0; k < 8; ++k) xs[k] = xr[k];
  float4 acc = ((const float4*)b)[q];
#pragma unroll
  for (int k = 0; k < 8; ++k) {
    float4 w = ((const float4*)(W + (size_t)k * 128))[q];
    acc.x += xs[k] * w.x; acc.y += xs[k] * w.y;
    acc.z += xs[k] * w.z; acc.w += xs[k] * w.w;
  }
  ((float4*)h)[idx] = acc;
  ushort4 hv4 = make_ushort4(f2bf(acc.x), f2bf(acc.y), f2bf(acc.z), f2bf(acc.w));
  *(ushort4*)(hb + (size_t)idx * 4) = hv4;
}

// ---------- edge weights -> MFMA B-fragment order (fp16) ----------
// eWf[l][nt][lane] = 2 uints = 4 halves: W[l][quad*4+i][nt*16+l15], i=0..3
// (mfma_16x16x16f16 B-layout: col = lane&15, k = (lane>>4)*4 + i)
__global__ __launch_bounds__(256) void k_wconv2(const float* __restrict__ eW,
    unsigned* __restrict__ eWf) {              // 4*8*64 uint2 = 4096 uints
  int i = blockIdx.x * 256 + threadIdx.x;      // one uint2 per thread
  if (i >= 2048) return;
  int lane = i & 63, nt = (i >> 6) & 7, l = i >> 9;
  int l15 = lane & 15, quad = lane >> 4;
  const float* base = eW + (size_t)l * 16 * 128 + (size_t)(nt * 16 + l15);
  unsigned lo = pack_h2(base[(quad * 4 + 0) * 128], base[(quad * 4 + 1) * 128]);
  unsigned hi = pack_h2(base[(quad * 4 + 2) * 128], base[(quad * 4 + 3) * 128]);
  eWf[(size_t)i * 2] = lo;
  eWf[(size_t)i * 2 + 1] = hi;
}

// ---------- transpose nn_W to bf16: WT[l][n][k] = bf16(nn_W[l][k][n]) ----------
__global__ __launch_bounds__(256) void k_nnconv(const float* __restrict__ W,
    unsigned short* __restrict__ WT) {
  int i = blockIdx.x * 256 + threadIdx.x;    // i = ((l*128)+k)*128 + n
  if (i >= 4 * 128 * 128) return;
  int n = i & 127, k = (i >> 7) & 127, l = i >> 14;
  WT[((size_t)(l * 128 + n)) * 128 + k] = f2bf(W[i]);
}

// ---------- CSR build ----------
__global__ void k_hist(const int* __restrict__ dst, int* __restrict__ deg, int E) {
  int e = blockIdx.x * blockDim.x + threadIdx.x;
  if (e < E) atomicAdd(&deg[dst[e]], 1);
}

__global__ __launch_bounds__(256) void k_scan_reduce(const int* __restrict__ deg,
    int* __restrict__ bsum, int N) {
  __shared__ int sd[256];
  int i = blockIdx.x * 256 + threadIdx.x;
  sd[threadIdx.x] = (i < N) ? deg[i] : 0;
  __syncthreads();
  for (int s = 128; s > 0; s >>= 1) {
    if (threadIdx.x < s) sd[threadIdx.x] += sd[threadIdx.x + s];
    __syncthreads();
  }
  if (threadIdx.x == 0) bsum[blockIdx.x] = sd[0];
}

// single-block exclusive scan over nb (<=512) block sums
__global__ __launch_bounds__(512) void k_scan_mid(int* bsum, int nb) {
  __shared__ int sd[512];
  int t = threadIdx.x;
  int v = (t < nb) ? bsum[t] : 0;
  sd[t] = v; __syncthreads();
  for (int d = 1; d < 512; d <<= 1) {
    int xv = (t >= d) ? sd[t - d] : 0;
    __syncthreads();
    sd[t] += xv;
    __syncthreads();
  }
  if (t < nb) bsum[t] = sd[t] - v;   // exclusive
}

__global__ __launch_bounds__(256) void k_scan_final(const int* __restrict__ deg,
    const int* __restrict__ bsum, int* __restrict__ offs,
    int* __restrict__ cursor, int N) {
  __shared__ int sd[256];
  int t = threadIdx.x;
  int i = blockIdx.x * 256 + t;
  int v = (i < N) ? deg[i] : 0;
  sd[t] = v; __syncthreads();
  for (int d = 1; d < 256; d <<= 1) {           // Hillis-Steele inclusive scan
    int xv = (t >= d) ? sd[t - d] : 0;
    __syncthreads();
    sd[t] += xv;
    __syncthreads();
  }
  int off = bsum[blockIdx.x] + sd[t] - v;       // exclusive
  if (i < N) {
    offs[i] = off; cursor[i] = off;
    if (i == N - 1) offs[N] = off + v;
  }
}

// fill CSR: permute src + attr (converted to fp16, 32 B/edge) into dst order
__global__ void k_fill(const int* __restrict__ src, const int* __restrict__ dst,
    const float* __restrict__ attr, int* __restrict__ cursor,
    int* __restrict__ csrc, uint4* __restrict__ cattr16, int E) {
  int e = blockIdx.x * blockDim.x + threadIdx.x;
  if (e >= E) return;
  int d = dst[e];
  int pos = atomicAdd(&cursor[d], 1);
  csrc[pos] = src[e];
  const float4* a = (const float4*)(attr + (size_t)e * 16);
  float4 a0 = a[0], a1 = a[1], a2 = a[2], a3 = a[3];
  uint4 o0, o1;
  o0.x = pack_h2(a0.x, a0.y); o0.y = pack_h2(a0.z, a0.w);
  o0.z = pack_h2(a1.x, a1.y); o0.w = pack_h2(a1.z, a1.w);
  o1.x = pack_h2(a2.x, a2.y); o1.y = pack_h2(a2.z, a2.w);
  o1.z = pack_h2(a3.x, a3.y); o1.w = pack_h2(a3.z, a3.w);
  cattr16[(size_t)pos * 2] = o0;
  cattr16[(size_t)pos * 2 + 1] = o1;
}

// ---------- graph boundaries (batch is sorted) ----------
__global__ void k_gstart(const int* __restrict__ batch, int* __restrict__ gstart,
                         int N, int Gn) {
  int i = blockIdx.x * blockDim.x + threadIdx.x;
  if (i >= N) return;
  int b = batch[i];
  if (i == 0) { for (int g = 0; g <= b; ++g) gstart[g] = 0; }
  else { int bp = batch[i - 1]; for (int g = bp + 1; g <= b; ++g) gstart[g] = i; }
  if (i == N - 1) { for (int g = b + 1; g <= Gn; ++g) gstart[g] = N; }
}

// ---------- fused edge embed + gather + relu + aggregate (v6: MFMA edge-MLP) ----------
// hpa16[n] = bf16( h[n] + sum_j relu( attr[j]@edge_W + edge_b + h[src[j]] ) )
// Wave per node (wave-stride). Per 16-edge group:
//   e[16x128] = attr[16x16] @ W[16x128] via 8x mfma_f32_16x16x16f16,
//   e-tile -> per-wave LDS [16][132] f32 (2-way conflicts only, no barrier),
//   then per-edge epilogue: lane owns cols 2l,2l+1: ds_read_b64 + bf16 gather
//   of h[src] + bias + relu + accumulate. Ragged tails = masked full groups
//   (wave-uniform guards; csrc/cattr have slack allocations).
__global__ __launch_bounds__(256) void k_edge_agg(const float* __restrict__ h,
    const unsigned* __restrict__ hb32,       // bf16 shadow viewed as uint
    const uint4* __restrict__ cattr16, const int* __restrict__ csrc,
    const int* __restrict__ offs, const unsigned* __restrict__ eWf,
    const float* __restrict__ eb, unsigned* __restrict__ hpa16,
    float* __restrict__ cstats, int N) {
  __shared__ float elds_all[4][16 * 132];
  int t = threadIdx.x;
  if (blockIdx.x == 0) cstats[t] = 0.f;    // 256 floats: colsum|colsumsq
  int lane = t & 63;                        // lane -> columns 2l, 2l+1
  int l15 = lane & 15, quad = lane >> 4;
  int wid = blockIdx.x * 4 + (t >> 6);
  int nw = gridDim.x * 4;
  float* elds = elds_all[t >> 6];
  uint2 bfr[8];                             // B-fragments (whole W in regs)
#pragma unroll
  for (int nt = 0; nt < 8; ++nt) bfr[nt] = ((const uint2*)eWf)[nt * 64 + lane];
  float2 bias = *(const float2*)(eb + 2 * lane);
  const unsigned* hb_l = hb32 + lane;       // + s*64 per edge (row = 64 uints)

// guarded gather issue (wave-uniform branch; SGPR src id -> SALU addressing)
#define GI(r, SC)                                                           \
  unsigned u##r = 0;                                                        \
  if (j0 + (r) < je) u##r = hb_l[(size_t)(unsigned)(SC) * 64];

// guarded per-edge combine
#define EPI(r, UU, AX, AY)                                                  \
  if (j0 + (r) < je) {                                                      \
    float2 ev = *(const float2*)&elds[(r) * 132 + 2 * lane];                \
    union { unsigned uu; float ff; } c0, c1;                                \
    c0.uu = (UU) << 16; c1.uu = (UU) & 0xffff0000u;                         \
    AX += fmaxf(ev.x + bias.x + c0.ff, 0.f);                                \
    AY += fmaxf(ev.y + bias.y + c1.ff, 0.f);                                \
  }

  for (int n = wid; n < N; n += nw) {
    int jb = __builtin_amdgcn_readfirstlane(offs[n]);
    int je = __builtin_amdgcn_readfirstlane(offs[n + 1]);
    float ax = 0.f, ay = 0.f, bx = 0.f, by = 0.f;
    for (int j0 = jb; j0 < je; j0 += 16) {
      // src ids for the group (SMEM)
      uint8v scA = sload8((const char*)csrc + ((size_t)(unsigned)j0 << 2));
      uint8v scB = sload8((const char*)csrc + ((size_t)(unsigned)(j0 + 8) << 2));
      // A-fragment: attr[edge l15][k quad*4..+3] — issue BEFORE the fence so
      // it is older than the gathers (MFMA then waits vmcnt(16), not 0).
      uint2 araw = *(const uint2*)((const char*)cattr16 +
                    ((size_t)(unsigned)(j0 + l15)) * 32 + quad * 8);
      swait();   // csrc ready; sched_barrier pins araw above, gathers below
      GI(0, scA[0]) GI(1, scA[1]) GI(2, scA[2]) GI(3, scA[3])
      GI(4, scA[4]) GI(5, scA[5]) GI(6, scA[6]) GI(7, scA[7])
      GI(8, scB[0]) GI(9, scB[1]) GI(10, scB[2]) GI(11, scB[3])
      GI(12, scB[4]) GI(13, scB[5]) GI(14, scB[6]) GI(15, scB[7])
      // e-tile = attr @ W  (8 col-tiles)
      half4v av;
      __builtin_memcpy(&av, &araw, 8);
      f32x4 ee[8];
#pragma unroll
      for (int nt = 0; nt < 8; ++nt) {
        half4v bv;
        __builtin_memcpy(&bv, &bfr[nt], 8);
        ee[nt] = __builtin_amdgcn_mfma_f32_16x16x16f16(
            av, bv, (f32x4){0.f, 0.f, 0.f, 0.f}, 0, 0, 0);
      }
      // scatter e-tile to LDS: row = edge (quad*4+reg), col = nt*16+l15
#pragma unroll
      for (int nt = 0; nt < 8; ++nt)
#pragma unroll
        for (int reg = 0; reg < 4; ++reg)
          elds[(quad * 4 + reg) * 132 + nt * 16 + l15] = ee[nt][reg];
      // per-edge combine (compiler inserts lgkmcnt before elds reads)
      EPI(0, u0, ax, ay)  EPI(1, u1, bx, by)
      EPI(2, u2, ax, ay)  EPI(3, u3, bx, by)
      EPI(4, u4, ax, ay)  EPI(5, u5, bx, by)
      EPI(6, u6, ax, ay)  EPI(7, u7, bx, by)
      EPI(8, u8, ax, ay)  EPI(9, u9, bx, by)
      EPI(10, u10, ax, ay) EPI(11, u11, bx, by)
      EPI(12, u12, ax, ay) EPI(13, u13, bx, by)
      EPI(14, u14, ax, ay) EPI(15, u15, bx, by)
    }
    float2 hvv = *(const float2*)(h + (size_t)n * 128 + 2 * lane);
    float rx = hvv.x + ax + bx;
    float ry = hvv.y + ay + by;
    hpa16[(size_t)n * 64 + lane] = ((unsigned)f2bf(ry) << 16) | (unsigned)f2bf(rx);
  }
#undef GI
#undef EPI
}

// ---------- MFMA node GEMM: hc = bf16(hpa) @ nn_W + nn_b, + fused BN stats ----------
// 128 rows/block, 4 waves x (2 row-tiles x 8 col-tiles) of 16x16x32 bf16 MFMA.
// A and WT (pre-transposed W, [n][k]) staged in LDS, rows padded +8 shorts
// (272 B stride -> 2-way bank aliasing, free). Stats: shfl-xor quad reduce ->
// LDS -> 256 atomics per block.
__global__ __launch_bounds__(256) void k_gemm_mfma(
    const unsigned short* __restrict__ A16, const unsigned short* __restrict__ WT16,
    const float* __restrict__ bias, float* __restrict__ hc,
    float* __restrict__ cstats, int N) {
  __shared__ short a_lds[128 * 136];
  __shared__ short w_lds[128 * 136];
  int t = threadIdx.x;
  int rowbase = blockIdx.x * 128;
  {
    int r = t >> 1;
    int off = (t & 1) * 64;              // shorts
    const short* ga = (const short*)A16 + (size_t)(rowbase + r) * 128 + off;
    short* la = &a_lds[r * 136 + off];
    const short* gw = (const short*)WT16 + (size_t)r * 128 + off;
    short* lw = &w_lds[r * 136 + off];
    if (rowbase + r < N) {
#pragma unroll
      for (int jj = 0; jj < 8; ++jj)
        *(uint4*)(la + jj * 8) = *(const uint4*)(ga + jj * 8);
    } else {
#pragma unroll
      for (int jj = 0; jj < 8; ++jj)
        *(uint4*)(la + jj * 8) = make_uint4(0, 0, 0, 0);
    }
#pragma unroll
    for (int jj = 0; jj < 8; ++jj)
      *(uint4*)(lw + jj * 8) = *(const uint4*)(gw + jj * 8);
  }
  __syncthreads();
  int w = t >> 6;
  int lane = t & 63;
  int l15 = lane & 15, quad = lane >> 4;
  f32x4 acc[2][8];
#pragma unroll
  for (int rt = 0; rt < 2; ++rt)
#pragma unroll
    for (int nt = 0; nt < 8; ++nt)
      acc[rt][nt] = (f32x4){0.f, 0.f, 0.f, 0.f};
#pragma unroll
  for (int kc = 0; kc < 4; ++kc) {
    int k0 = kc * 32 + quad * 8;
    short8 af0 = *(const short8*)&a_lds[(w * 32 + l15) * 136 + k0];
    short8 af1 = *(const short8*)&a_lds[(w * 32 + 16 + l15) * 136 + k0];
#pragma unroll
    for (int nt = 0; nt < 8; ++nt) {
      short8 bf = *(const short8*)&w_lds[(nt * 16 + l15) * 136 + k0];
      acc[0][nt] = __builtin_amdgcn_mfma_f32_16x16x32_bf16(af0, bf, acc[0][nt], 0, 0, 0);
      acc[1][nt] = __builtin_amdgcn_mfma_f32_16x16x32_bf16(af1, bf, acc[1][nt], 0, 0, 0);
    }
  }
  float sA[8], sQ[8];
#pragma unroll
  for (int nt = 0; nt < 8; ++nt) { sA[nt] = 0.f; sQ[nt] = 0.f; }
#pragma unroll
  for (int nt = 0; nt < 8; ++nt) {
    int col = nt * 16 + l15;
    float bv = bias[col];
#pragma unroll
    for (int rt = 0; rt < 2; ++rt) {
      int rbase = rowbase + w * 32 + rt * 16 + quad * 4;
#pragma unroll
      for (int reg = 0; reg < 4; ++reg) {
        int row = rbase + reg;
        float v = acc[rt][nt][reg] + bv;
        if (row < N) {
          hc[(size_t)row * 128 + col] = v;
          sA[nt] += v; sQ[nt] += v * v;
        }
      }
    }
  }
#pragma unroll
  for (int nt = 0; nt < 8; ++nt) {
    sA[nt] += __shfl_xor(sA[nt], 16);
    sA[nt] += __shfl_xor(sA[nt], 32);
    sQ[nt] += __shfl_xor(sQ[nt], 16);
    sQ[nt] += __shfl_xor(sQ[nt], 32);
  }
  __syncthreads();                    // done with a_lds/w_lds contents
  float* sdA = (float*)a_lds;         // [4][128]
  float* sdQ = (float*)w_lds;
  if (quad == 0) {
#pragma unroll
    for (int nt = 0; nt < 8; ++nt) {
      sdA[w * 128 + nt * 16 + l15] = sA[nt];
      sdQ[w * 128 + nt * 16 + l15] = sQ[nt];
    }
  }
  __syncthreads();
  if (t < 128) {
    float s = sdA[t] + sdA[128 + t] + sdA[256 + t] + sdA[384 + t];
    float s2 = sdQ[t] + sdQ[128 + t] + sdQ[256 + t] + sdQ[384 + t];
    atomicAdd(&cstats[t], s);
    atomicAdd(&cstats[128 + t], s2);
  }
}

// ---------- BN apply + exact GELU + residual: h += gelu(bn(hc)); bf16 shadow ----------
__global__ __launch_bounds__(256) void k_bn(const float* __restrict__ hc,
    const float* __restrict__ cstats,
    const float* __restrict__ g, const float* __restrict__ bb,
    float* __restrict__ h, unsigned short* __restrict__ hb, int N) {
  int idx = blockIdx.x * 256 + threadIdx.x;
  if (idx >= N * 32) return;
  int q = idx & 31;
  float invN = 1.f / (float)N;
  float4 cs = ((const float4*)cstats)[q];
  float4 cq = ((const float4*)cstats)[q + 32];
  float4 gv = ((const float4*)g)[q];
  float4 bv = ((const float4*)bb)[q];
  float4 v = ((const float4*)hc)[idx];
  float4 hv = ((const float4*)h)[idx];
#define BN1(X)                                                      \
  { float mu = cs.X * invN;                                         \
    float var = cq.X * invN - mu * mu;                              \
    float xn = (v.X - mu) * rsqrtf(var + 1e-5f) * gv.X + bv.X;      \
    hv.X += 0.5f * xn * (1.f + erff(xn * 0.70710678118654752f)); }
  BN1(x) BN1(y) BN1(z) BN1(w)
#undef BN1
  ((float4*)h)[idx] = hv;
  if (hb) {
    ushort4 hv4 = make_ushort4(f2bf(hv.x), f2bf(hv.y), f2bf(hv.z), f2bf(hv.w));
    *(ushort4*)(hb + (size_t)idx * 4) = hv4;
  }
}

// ---------- rep[g] = (sum over nodes of graph g of h[n]) @ lin_W + cnt*lin_b ----------
__global__ __launch_bounds__(256) void k_poolfinal(const float* __restrict__ h,
    const int* __restrict__ gstart, const float* __restrict__ W,
    const float* __restrict__ b, float* __restrict__ out) {
  int g = blockIdx.x;
  int t = threadIdx.x, c = t & 127, half = t >> 7;
  int n0 = gstart[g], n1 = gstart[g + 1];
  float s = 0.f;
  for (int n = n0 + half; n < n1; n += 2) s += h[(size_t)n * 128 + c];
  __shared__ float ls[256];
  __shared__ float pr[128];
  ls[t] = s; __syncthreads();
  if (t < 128) pr[t] = ls[t] + ls[t + 128];
  __syncthreads();
  float cnt = (float)(n1 - n0);
  float acc = cnt * b[t];
#pragma unroll 8
  for (int k = 0; k < 128; ++k) acc += pr[k] * W[(size_t)k * 256 + t];
  out[(size_t)g * 256 + t] = acc;
}

extern "C" void kernel_launch(void* const* d_in, const int* in_sizes, int n_in,
                              void* d_out, int out_size, void* d_ws, size_t ws_size,
                              hipStream_t stream) {
  const float* x     = (const float*)d_in[0];
  const int*   eidx  = (const int*)d_in[1];
  const float* eattr = (const float*)d_in[2];
  const int*   batch = (const int*)d_in[3];
  const float* embW  = (const float*)d_in[4];
  const float* embB  = (const float*)d_in[5];
  const float* edgeW = (const float*)d_in[6];
  const float* edgeB = (const float*)d_in[7];
  const float* nnW   = (const float*)d_in[8];
  const float* nnB   = (const float*)d_in[9];
  const float* bnG   = (const float*)d_in[10];
  const float* bnB   = (const float*)d_in[11];
  const float* linW  = (const float*)d_in[12];
  const float* linB  = (const float*)d_in[13];
  float* out = (float*)d_out;

  int N = in_sizes[0] / 8;
  int E = in_sizes[1] / 2;
  const int* src = eidx;
  const int* dst = eidx + E;

  // workspace carve-up (~220 MB); cattr16/csrc get 16-edge slack for masked
  // group loads past je at the array end.
  char* wptr = (char*)d_ws;
  auto alloc = [&](size_t bytes) {
    char* p = wptr; wptr += (bytes + 255) & ~(size_t)255; return p;
  };
  float* h      = (float*)alloc((size_t)N * 128 * 4);
  float* hc     = (float*)alloc((size_t)N * 128 * 4);   // fp32 GEMM output
  unsigned short* hb = (unsigned short*)alloc((size_t)N * 128 * 2);  // bf16 h shadow
  unsigned* hpa16 = (unsigned*)alloc((size_t)N * 64 * 4);  // bf16 h+agg (GEMM input)
  uint4* cattr16 = (uint4*)alloc((size_t)E * 32 + 1024); // fp16 attrs + slack
  int*   csrc   = (int*)alloc((size_t)E * 4 + 256);      // + slack
  int*   offs   = (int*)alloc((size_t)(N + 1) * 4);
  int*   cursor = (int*)alloc((size_t)N * 4);
  int*   deg    = (int*)alloc((size_t)N * 4);
  int nb = (N + 255) / 256;
  int*   bsum   = (int*)alloc((size_t)nb * 4);
  float* cstats = (float*)alloc(256 * 4);               // colsum | colsumsq
  unsigned* eWf = (unsigned*)alloc(4096 * 4);           // [4][8][64] B-frag uint2
  unsigned short* WT16 = (unsigned short*)alloc(4 * 128 * 128 * 2);  // bf16 W^T
  int*   gstart = (int*)alloc((size_t)(GG + 1) * 4);

  int q32 = (N * 32 + 255) / 256;

  hipMemsetAsync(deg, 0, (size_t)N * 4, stream);
  k_emb<<<q32, 256, 0, stream>>>(x, embW, embB, h, hb, N);
  k_wconv2<<<8, 256, 0, stream>>>(edgeW, eWf);
  k_nnconv<<<256, 256, 0, stream>>>(nnW, WT16);
  k_hist<<<(E + 255) / 256, 256, 0, stream>>>(dst, deg, E);
  k_scan_reduce<<<nb, 256, 0, stream>>>(deg, bsum, N);
  k_scan_mid<<<1, 512, 0, stream>>>(bsum, nb);
  k_scan_final<<<nb, 256, 0, stream>>>(deg, bsum, offs, cursor, N);
  k_fill<<<(E + 255) / 256, 256, 0, stream>>>(src, dst, eattr, cursor, csrc, cattr16, E);
  k_gstart<<<(N + 255) / 256, 256, 0, stream>>>(batch, gstart, N, GG);

  int gblk = (N + 127) / 128;
  for (int l = 0; l < 4; ++l) {
    k_edge_agg<<<8192, 256, 0, stream>>>(h, (const unsigned*)hb, cattr16, csrc,
        offs, eWf + (size_t)l * 1024, edgeB + (size_t)l * 128, hpa16, cstats, N);
    k_gemm_mfma<<<gblk, 256, 0, stream>>>((const unsigned short*)hpa16,
        WT16 + (size_t)l * 128 * 128, nnB + (size_t)l * 128, hc, cstats, N);
    k_bn<<<q32, 256, 0, stream>>>(hc, cstats,
        bnG + (size_t)l * 128, bnB + (size_t)l * 128, h, (l == 3) ? nullptr : hb, N);
  }
  k_poolfinal<<<GG, 256, 0, stream>>>(h, gstart, linW, linB, out);
}

// Round 7
// 1027.943 us; speedup vs baseline: 1.3045x; 1.0351x over previous
//
#include <hip/hip_runtime.h>
#include <hip/hip_fp16.h>
#include <math.h>

// Problem constants (from reference): N=100000, E=1600000, F_IN=8, H=128,
// L=4, E_FEAT=16, G=256, OUT=256. N/E derived from in_sizes at launch.
#define GG 256

typedef __attribute__((ext_vector_type(8))) short short8;
typedef __attribute__((ext_vector_type(4))) float f32x4;
typedef _Float16 half4v __attribute__((ext_vector_type(4)));
typedef __attribute__((ext_vector_type(8))) unsigned uint8v;

__device__ __forceinline__ unsigned short f2bf(float x) {
  union { float f; unsigned u; } v; v.f = x;
  unsigned r = v.u + 0x7fff + ((v.u >> 16) & 1);   // round-to-nearest-even
  return (unsigned short)(r >> 16);
}

__device__ __forceinline__ unsigned pack_h2(float a, float b) {
  __half2 h = __floats2half2_rn(a, b);
  return *(unsigned*)&h;
}

// scalar load (wave-uniform address) — SMEM path, SALU addressing
__device__ __forceinline__ uint8v sload8(const void* p) {
  uint8v r;
  asm volatile("s_load_dwordx8 %0, %1, 0x0"
               : "=s"(r) : "s"((unsigned long long)p));
  return r;
}
__device__ __forceinline__ void swait() {
  asm volatile("s_waitcnt lgkmcnt(0)" ::: "memory");
  __builtin_amdgcn_sched_barrier(0);   // rule #18: pin consumers after the wait
}
// drain SMEM with the pending registers tied THROUGH the asm ("+s"), so any
// consumer/copy of them is ordered after the waitcnt (SGPR-read-race safe).
__device__ __forceinline__ void swait2(uint8v& a, uint8v& b) {
  asm volatile("s_waitcnt lgkmcnt(0)" : "+s"(a), "+s"(b) :: "memory");
  __builtin_amdgcn_sched_barrier(0);
}

// ---------- h = x @ emb_W + emb_b  ([N,8]@[8,128]); also writes bf16 shadow ----------
__global__ __launch_bounds__(256) void k_emb(const float* __restrict__ x,
    const float* __restrict__ W, const float* __restrict__ b,
    float* __restrict__ h, unsigned short* __restrict__ hb, int N) {
  int idx = blockIdx.x * 256 + threadIdx.x;      // one float4 of output per thread
  if (idx >= N * 32) return;
  int n = idx >> 5, q = idx & 31;
  const float* xr = x + (size_t)n * 8;
  float xs[8];
#pragma unroll
  for (int k = 0; k < 8; ++k) xs[k] = xr[k];
  float4 acc = ((const float4*)b)[q];
#pragma unroll
  for (int k = 0; k < 8; ++k) {
    float4 w = ((const float4*)(W + (size_t)k * 128))[q];
    acc.x += xs[k] * w.x; acc.y += xs[k] * w.y;
    acc.z += xs[k] * w.z; acc.w += xs[k] * w.w;
  }
  ((float4*)h)[idx] = acc;
  ushort4 hv4 = make_ushort4(f2bf(acc.x), f2bf(acc.y), f2bf(acc.z), f2bf(acc.w));
  *(ushort4*)(hb + (size_t)idx * 4) = hv4;
}

// ---------- edge weights -> MFMA B-fragment order (fp16) ----------
// eWf[l][nt][lane] = 2 uints = 4 halves: W[l][quad*4+i][nt*16+l15], i=0..3
// (mfma_16x16x16f16 B-layout: col = lane&15, k = (lane>>4)*4 + i)
__global__ __launch_bounds__(256) void k_wconv2(const float* __restrict__ eW,
    unsigned* __restrict__ eWf) {              // 4*8*64 uint2 = 4096 uints
  int i = blockIdx.x * 256 + threadIdx.x;      // one uint2 per thread
  if (i >= 2048) return;
  int lane = i & 63, nt = (i >> 6) & 7, l = i >> 9;
  int l15 = lane & 15, quad = lane >> 4;
  const float* base = eW + (size_t)l * 16 * 128 + (size_t)(nt * 16 + l15);
  unsigned lo = pack_h2(base[(quad * 4 + 0) * 128], base[(quad * 4 + 1) * 128]);
  unsigned hi = pack_h2(base[(quad * 4 + 2) * 128], base[(quad * 4 + 3) * 128]);
  eWf[(size_t)i * 2] = lo;
  eWf[(size_t)i * 2 + 1] = hi;
}

// ---------- transpose nn_W to bf16: WT[l][n][k] = bf16(nn_W[l][k][n]) ----------
__global__ __launch_bounds__(256) void k_nnconv(const float* __restrict__ W,
    unsigned short* __restrict__ WT) {
  int i = blockIdx.x * 256 + threadIdx.x;    // i = ((l*128)+k)*128 + n
  if (i >= 4 * 128 * 128) return;
  int n = i & 127, k = (i >> 7) & 127, l = i >> 14;
  WT[((size_t)(l * 128 + n)) * 128 + k] = f2bf(W[i]);
}

// ---------- CSR build ----------
__global__ void k_hist(const int* __restrict__ dst, int* __restrict__ deg, int E) {
  int e = blockIdx.x * blockDim.x + threadIdx.x;
  if (e < E) atomicAdd(&deg[dst[e]], 1);
}

__global__ __launch_bounds__(256) void k_scan_reduce(const int* __restrict__ deg,
    int* __restrict__ bsum, int N) {
  __shared__ int sd[256];
  int i = blockIdx.x * 256 + threadIdx.x;
  sd[threadIdx.x] = (i < N) ? deg[i] : 0;
  __syncthreads();
  for (int s = 128; s > 0; s >>= 1) {
    if (threadIdx.x < s) sd[threadIdx.x] += sd[threadIdx.x + s];
    __syncthreads();
  }
  if (threadIdx.x == 0) bsum[blockIdx.x] = sd[0];
}

// single-block exclusive scan over nb (<=512) block sums
__global__ __launch_bounds__(512) void k_scan_mid(int* bsum, int nb) {
  __shared__ int sd[512];
  int t = threadIdx.x;
  int v = (t < nb) ? bsum[t] : 0;
  sd[t] = v; __syncthreads();
  for (int d = 1; d < 512; d <<= 1) {
    int xv = (t >= d) ? sd[t - d] : 0;
    __syncthreads();
    sd[t] += xv;
    __syncthreads();
  }
  if (t < nb) bsum[t] = sd[t] - v;   // exclusive
}

__global__ __launch_bounds__(256) void k_scan_final(const int* __restrict__ deg,
    const int* __restrict__ bsum, int* __restrict__ offs,
    int* __restrict__ cursor, int N) {
  __shared__ int sd[256];
  int t = threadIdx.x;
  int i = blockIdx.x * 256 + t;
  int v = (i < N) ? deg[i] : 0;
  sd[t] = v; __syncthreads();
  for (int d = 1; d < 256; d <<= 1) {           // Hillis-Steele inclusive scan
    int xv = (t >= d) ? sd[t - d] : 0;
    __syncthreads();
    sd[t] += xv;
    __syncthreads();
  }
  int off = bsum[blockIdx.x] + sd[t] - v;       // exclusive
  if (i < N) {
    offs[i] = off; cursor[i] = off;
    if (i == N - 1) offs[N] = off + v;
  }
}

// fill CSR: permute src + attr (converted to fp16, 32 B/edge) into dst order
__global__ void k_fill(const int* __restrict__ src, const int* __restrict__ dst,
    const float* __restrict__ attr, int* __restrict__ cursor,
    int* __restrict__ csrc, uint4* __restrict__ cattr16, int E) {
  int e = blockIdx.x * blockDim.x + threadIdx.x;
  if (e >= E) return;
  int d = dst[e];
  int pos = atomicAdd(&cursor[d], 1);
  csrc[pos] = src[e];
  const float4* a = (const float4*)(attr + (size_t)e * 16);
  float4 a0 = a[0], a1 = a[1], a2 = a[2], a3 = a[3];
  uint4 o0, o1;
  o0.x = pack_h2(a0.x, a0.y); o0.y = pack_h2(a0.z, a0.w);
  o0.z = pack_h2(a1.x, a1.y); o0.w = pack_h2(a1.z, a1.w);
  o1.x = pack_h2(a2.x, a2.y); o1.y = pack_h2(a2.z, a2.w);
  o1.z = pack_h2(a3.x, a3.y); o1.w = pack_h2(a3.z, a3.w);
  cattr16[(size_t)pos * 2] = o0;
  cattr16[(size_t)pos * 2 + 1] = o1;
}

// ---------- graph boundaries (batch is sorted) ----------
__global__ void k_gstart(const int* __restrict__ batch, int* __restrict__ gstart,
                         int N, int Gn) {
  int i = blockIdx.x * blockDim.x + threadIdx.x;
  if (i >= N) return;
  int b = batch[i];
  if (i == 0) { for (int g = 0; g <= b; ++g) gstart[g] = 0; }
  else { int bp = batch[i - 1]; for (int g = bp + 1; g <= b; ++g) gstart[g] = i; }
  if (i == N - 1) { for (int g = b + 1; g <= Gn; ++g) gstart[g] = N; }
}

// ---------- fused edge embed + gather + relu + aggregate (v7) ----------
// hpa16[n] = bf16( h[n] + sum_j relu( attr[j]@edge_W + edge_b + h[src[j]] ) )
// Wave per node (wave-stride). Per 16-edge group:
//   e[16x128] = attr[16x16] @ W[16x128] via 8x mfma_f32_16x16x16f16,
//   e-tile -> per-wave LDS [16][136] __half (conflict-free; halves LDS vs f32
//   -> 8 blocks/CU occupancy cap), then per-edge epilogue (lane = col pair).
// Cross-group prefetch: next group's csrc s_loads + attr A-frag issued before
// the current epilogue; SGPR ping-pong drained via swait2 ("+s"-tied).
__global__ __launch_bounds__(256) void k_edge_agg(const float* __restrict__ h,
    const unsigned* __restrict__ hb32,       // bf16 shadow viewed as uint
    const uint4* __restrict__ cattr16, const int* __restrict__ csrc,
    const int* __restrict__ offs, const unsigned* __restrict__ eWf,
    const float* __restrict__ eb, unsigned* __restrict__ hpa16,
    float* __restrict__ cstats, int N) {
  __shared__ __half elds_all[4][16 * 136];
  int t = threadIdx.x;
  if (blockIdx.x == 0) cstats[t] = 0.f;    // 256 floats: colsum|colsumsq
  int lane = t & 63;                        // lane -> columns 2*lane, 2*lane+1
  int l15 = lane & 15, quad = lane >> 4;
  int wid = blockIdx.x * 4 + (t >> 6);
  int nw = gridDim.x * 4;
  __half* elds = elds_all[t >> 6];
  uint2 bfr[8];                             // B-fragments (whole W in regs)
#pragma unroll
  for (int nt = 0; nt < 8; ++nt) bfr[nt] = ((const uint2*)eWf)[nt * 64 + lane];
  float2 bias = *(const float2*)(eb + 2 * lane);
  const unsigned* hb_l = hb32 + lane;       // + s*64 per edge (row = 64 uints)

// guarded gather issue (wave-uniform branch; SGPR src id -> SALU addressing)
#define GI(r, SC)                                                           \
  unsigned u##r = 0;                                                        \
  if (j0 + (r) < je) u##r = hb_l[(size_t)(unsigned)(SC) * 64];

// guarded per-edge combine (e from f16 LDS)
#define EPI(r, UU, AX, AY)                                                  \
  if (j0 + (r) < je) {                                                      \
    __half2 ev2 = *(__half2*)&elds[(r) * 136 + 2 * lane];                   \
    union { unsigned uu; float ff; } c0, c1;                                \
    c0.uu = (UU) << 16; c1.uu = (UU) & 0xffff0000u;                         \
    AX += fmaxf(__low2float(ev2) + bias.x + c0.ff, 0.f);                    \
    AY += fmaxf(__high2float(ev2) + bias.y + c1.ff, 0.f);                   \
  }

#define LOADA(DST, J0)                                                      \
  DST = *(const uint2*)((const char*)cattr16 +                              \
        ((size_t)(unsigned)((J0) + l15)) * 32 + quad * 8);

  for (int n = wid; n < N; n += nw) {
    int jb = __builtin_amdgcn_readfirstlane(offs[n]);
    int je = __builtin_amdgcn_readfirstlane(offs[n + 1]);
    float ax = 0.f, ay = 0.f, bx = 0.f, by = 0.f;
    if (jb < je) {
      uint8v scA = sload8((const char*)csrc + ((size_t)(unsigned)jb << 2));
      uint8v scB = sload8((const char*)csrc + ((size_t)(unsigned)(jb + 8) << 2));
      uint2 araw;
      LOADA(araw, jb)
      swait2(scA, scB);
      for (int j0 = jb;;) {
        // gathers for this group (oldest VMEM; epilogue waits only for these)
        GI(0, scA[0]) GI(1, scA[1]) GI(2, scA[2]) GI(3, scA[3])
        GI(4, scA[4]) GI(5, scA[5]) GI(6, scA[6]) GI(7, scA[7])
        GI(8, scB[0]) GI(9, scB[1]) GI(10, scB[2]) GI(11, scB[3])
        GI(12, scB[4]) GI(13, scB[5]) GI(14, scB[6]) GI(15, scB[7])
        bool more = (j0 + 16 < je);
        uint8v scA2, scB2;
        uint2 araw2;
        if (more) {
          scA2 = sload8((const char*)csrc + ((size_t)(unsigned)(j0 + 16) << 2));
          scB2 = sload8((const char*)csrc + ((size_t)(unsigned)(j0 + 24) << 2));
          LOADA(araw2, j0 + 16)          // younger than gathers: stays in flight
        }
        // e-tile = attr @ W  (8 col-tiles)
        half4v av;
        __builtin_memcpy(&av, &araw, 8);
        f32x4 ee[8];
#pragma unroll
        for (int nt = 0; nt < 8; ++nt) {
          half4v bv;
          __builtin_memcpy(&bv, &bfr[nt], 8);
          ee[nt] = __builtin_amdgcn_mfma_f32_16x16x16f16(
              av, bv, (f32x4){0.f, 0.f, 0.f, 0.f}, 0, 0, 0);
        }
        // scatter e-tile to LDS (f16): row = edge (quad*4+reg), col = nt*16+l15
#pragma unroll
        for (int nt = 0; nt < 8; ++nt)
#pragma unroll
          for (int reg = 0; reg < 4; ++reg)
            elds[(quad * 4 + reg) * 136 + nt * 16 + l15] =
                __float2half(ee[nt][reg]);
        // per-edge combine (compiler inserts lgkmcnt/vmcnt before reads)
        EPI(0, u0, ax, ay)  EPI(1, u1, bx, by)
        EPI(2, u2, ax, ay)  EPI(3, u3, bx, by)
        EPI(4, u4, ax, ay)  EPI(5, u5, bx, by)
        EPI(6, u6, ax, ay)  EPI(7, u7, bx, by)
        EPI(8, u8, ax, ay)  EPI(9, u9, bx, by)
        EPI(10, u10, ax, ay) EPI(11, u11, bx, by)
        EPI(12, u12, ax, ay) EPI(13, u13, bx, by)
        EPI(14, u14, ax, ay) EPI(15, u15, bx, by)
        j0 += 16;
        if (!more) break;
        swait2(scA2, scB2);             // landed during MFMA/LDS/epilogue
        scA = scA2; scB = scB2; araw = araw2;
      }
    }
    float2 hvv = *(const float2*)(h + (size_t)n * 128 + 2 * lane);
    float rx = hvv.x + ax + bx;
    float ry = hvv.y + ay + by;
    hpa16[(size_t)n * 64 + lane] = ((unsigned)f2bf(ry) << 16) | (unsigned)f2bf(rx);
  }
#undef GI
#undef EPI
#undef LOADA
}

// ---------- MFMA node GEMM: hc = bf16(hpa) @ nn_W + nn_b, + fused BN stats ----------
// 128 rows/block, 4 waves x (2 row-tiles x 8 col-tiles) of 16x16x32 bf16 MFMA.
// A and WT (pre-transposed W, [n][k]) staged in LDS, rows padded +8 shorts
// (272 B stride -> 2-way bank aliasing, free). Stats: shfl-xor quad reduce ->
// LDS -> 256 atomics per block.
__global__ __launch_bounds__(256) void k_gemm_mfma(
    const unsigned short* __restrict__ A16, const unsigned short* __restrict__ WT16,
    const float* __restrict__ bias, float* __restrict__ hc,
    float* __restrict__ cstats, int N) {
  __shared__ short a_lds[128 * 136];
  __shared__ short w_lds[128 * 136];
  int t = threadIdx.x;
  int rowbase = blockIdx.x * 128;
  {
    int r = t >> 1;
    int off = (t & 1) * 64;              // shorts
    const short* ga = (const short*)A16 + (size_t)(rowbase + r) * 128 + off;
    short* la = &a_lds[r * 136 + off];
    const short* gw = (const short*)WT16 + (size_t)r * 128 + off;
    short* lw = &w_lds[r * 136 + off];
    if (rowbase + r < N) {
#pragma unroll
      for (int jj = 0; jj < 8; ++jj)
        *(uint4*)(la + jj * 8) = *(const uint4*)(ga + jj * 8);
    } else {
#pragma unroll
      for (int jj = 0; jj < 8; ++jj)
        *(uint4*)(la + jj * 8) = make_uint4(0, 0, 0, 0);
    }
#pragma unroll
    for (int jj = 0; jj < 8; ++jj)
      *(uint4*)(lw + jj * 8) = *(const uint4*)(gw + jj * 8);
  }
  __syncthreads();
  int w = t >> 6;
  int lane = t & 63;
  int l15 = lane & 15, quad = lane >> 4;
  f32x4 acc[2][8];
#pragma unroll
  for (int rt = 0; rt < 2; ++rt)
#pragma unroll
    for (int nt = 0; nt < 8; ++nt)
      acc[rt][nt] = (f32x4){0.f, 0.f, 0.f, 0.f};
#pragma unroll
  for (int kc = 0; kc < 4; ++kc) {
    int k0 = kc * 32 + quad * 8;
    short8 af0 = *(const short8*)&a_lds[(w * 32 + l15) * 136 + k0];
    short8 af1 = *(const short8*)&a_lds[(w * 32 + 16 + l15) * 136 + k0];
#pragma unroll
    for (int nt = 0; nt < 8; ++nt) {
      short8 bf = *(const short8*)&w_lds[(nt * 16 + l15) * 136 + k0];
      acc[0][nt] = __builtin_amdgcn_mfma_f32_16x16x32_bf16(af0, bf, acc[0][nt], 0, 0, 0);
      acc[1][nt] = __builtin_amdgcn_mfma_f32_16x16x32_bf16(af1, bf, acc[1][nt], 0, 0, 0);
    }
  }
  float sA[8], sQ[8];
#pragma unroll
  for (int nt = 0; nt < 8; ++nt) { sA[nt] = 0.f; sQ[nt] = 0.f; }
#pragma unroll
  for (int nt = 0; nt < 8; ++nt) {
    int col = nt * 16 + l15;
    float bv = bias[col];
#pragma unroll
    for (int rt = 0; rt < 2; ++rt) {
      int rbase = rowbase + w * 32 + rt * 16 + quad * 4;
#pragma unroll
      for (int reg = 0; reg < 4; ++reg) {
        int row = rbase + reg;
        float v = acc[rt][nt][reg] + bv;
        if (row < N) {
          hc[(size_t)row * 128 + col] = v;
          sA[nt] += v; sQ[nt] += v * v;
        }
      }
    }
  }
#pragma unroll
  for (int nt = 0; nt < 8; ++nt) {
    sA[nt] += __shfl_xor(sA[nt], 16);
    sA[nt] += __shfl_xor(sA[nt], 32);
    sQ[nt] += __shfl_xor(sQ[nt], 16);
    sQ[nt] += __shfl_xor(sQ[nt], 32);
  }
  __syncthreads();                    // done with a_lds/w_lds contents
  float* sdA = (float*)a_lds;         // [4][128]
  float* sdQ = (float*)w_lds;
  if (quad == 0) {
#pragma unroll
    for (int nt = 0; nt < 8; ++nt) {
      sdA[w * 128 + nt * 16 + l15] = sA[nt];
      sdQ[w * 128 + nt * 16 + l15] = sQ[nt];
    }
  }
  __syncthreads();
  if (t < 128) {
    float s = sdA[t] + sdA[128 + t] + sdA[256 + t] + sdA[384 + t];
    float s2 = sdQ[t] + sdQ[128 + t] + sdQ[256 + t] + sdQ[384 + t];
    atomicAdd(&cstats[t], s);
    atomicAdd(&cstats[128 + t], s2);
  }
}

// ---------- BN apply + exact GELU + residual: h += gelu(bn(hc)); bf16 shadow ----------
__global__ __launch_bounds__(256) void k_bn(const float* __restrict__ hc,
    const float* __restrict__ cstats,
    const float* __restrict__ g, const float* __restrict__ bb,
    float* __restrict__ h, unsigned short* __restrict__ hb, int N) {
  int idx = blockIdx.x * 256 + threadIdx.x;
  if (idx >= N * 32) return;
  int q = idx & 31;
  float invN = 1.f / (float)N;
  float4 cs = ((const float4*)cstats)[q];
  float4 cq = ((const float4*)cstats)[q + 32];
  float4 gv = ((const float4*)g)[q];
  float4 bv = ((const float4*)bb)[q];
  float4 v = ((const float4*)hc)[idx];
  float4 hv = ((const float4*)h)[idx];
#define BN1(X)                                                      \
  { float mu = cs.X * invN;                                         \
    float var = cq.X * invN - mu * mu;                              \
    float xn = (v.X - mu) * rsqrtf(var + 1e-5f) * gv.X + bv.X;      \
    hv.X += 0.5f * xn * (1.f + erff(xn * 0.70710678118654752f)); }
  BN1(x) BN1(y) BN1(z) BN1(w)
#undef BN1
  ((float4*)h)[idx] = hv;
  if (hb) {
    ushort4 hv4 = make_ushort4(f2bf(hv.x), f2bf(hv.y), f2bf(hv.z), f2bf(hv.w));
    *(ushort4*)(hb + (size_t)idx * 4) = hv4;
  }
}

// ---------- rep[g] = (sum over nodes of graph g of h[n]) @ lin_W + cnt*lin_b ----------
__global__ __launch_bounds__(256) void k_poolfinal(const float* __restrict__ h,
    const int* __restrict__ gstart, const float* __restrict__ W,
    const float* __restrict__ b, float* __restrict__ out) {
  int g = blockIdx.x;
  int t = threadIdx.x, c = t & 127, half = t >> 7;
  int n0 = gstart[g], n1 = gstart[g + 1];
  float s = 0.f;
  for (int n = n0 + half; n < n1; n += 2) s += h[(size_t)n * 128 + c];
  __shared__ float ls[256];
  __shared__ float pr[128];
  ls[t] = s; __syncthreads();
  if (t < 128) pr[t] = ls[t] + ls[t + 128];
  __syncthreads();
  float cnt = (float)(n1 - n0);
  float acc = cnt * b[t];
#pragma unroll 8
  for (int k = 0; k < 128; ++k) acc += pr[k] * W[(size_t)k * 256 + t];
  out[(size_t)g * 256 + t] = acc;
}

extern "C" void kernel_launch(void* const* d_in, const int* in_sizes, int n_in,
                              void* d_out, int out_size, void* d_ws, size_t ws_size,
                              hipStream_t stream) {
  const float* x     = (const float*)d_in[0];
  const int*   eidx  = (const int*)d_in[1];
  const float* eattr = (const float*)d_in[2];
  const int*   batch = (const int*)d_in[3];
  const float* embW  = (const float*)d_in[4];
  const float* embB  = (const float*)d_in[5];
  const float* edgeW = (const float*)d_in[6];
  const float* edgeB = (const float*)d_in[7];
  const float* nnW   = (const float*)d_in[8];
  const float* nnB   = (const float*)d_in[9];
  const float* bnG   = (const float*)d_in[10];
  const float* bnB   = (const float*)d_in[11];
  const float* linW  = (const float*)d_in[12];
  const float* linB  = (const float*)d_in[13];
  float* out = (float*)d_out;

  int N = in_sizes[0] / 8;
  int E = in_sizes[1] / 2;
  const int* src = eidx;
  const int* dst = eidx + E;

  // workspace carve-up (~220 MB); cattr16/csrc get 16-edge slack for masked
  // group loads past je at the array end.
  char* wptr = (char*)d_ws;
  auto alloc = [&](size_t bytes) {
    char* p = wptr; wptr += (bytes + 255) & ~(size_t)255; return p;
  };
  float* h      = (float*)alloc((size_t)N * 128 * 4);
  float* hc     = (float*)alloc((size_t)N * 128 * 4);   // fp32 GEMM output
  unsigned short* hb = (unsigned short*)alloc((size_t)N * 128 * 2);  // bf16 h shadow
  unsigned* hpa16 = (unsigned*)alloc((size_t)N * 64 * 4);  // bf16 h+agg (GEMM input)
  uint4* cattr16 = (uint4*)alloc((size_t)E * 32 + 1024); // fp16 attrs + slack
  int*   csrc   = (int*)alloc((size_t)E * 4 + 256);      // + slack
  int*   offs   = (int*)alloc((size_t)(N + 1) * 4);
  int*   cursor = (int*)alloc((size_t)N * 4);
  int*   deg    = (int*)alloc((size_t)N * 4);
  int nb = (N + 255) / 256;
  int*   bsum   = (int*)alloc((size_t)nb * 4);
  float* cstats = (float*)alloc(256 * 4);               // colsum | colsumsq
  unsigned* eWf = (unsigned*)alloc(4096 * 4);           // [4][8][64] B-frag uint2
  unsigned short* WT16 = (unsigned short*)alloc(4 * 128 * 128 * 2);  // bf16 W^T
  int*   gstart = (int*)alloc((size_t)(GG + 1) * 4);

  int q32 = (N * 32 + 255) / 256;

  hipMemsetAsync(deg, 0, (size_t)N * 4, stream);
  k_emb<<<q32, 256, 0, stream>>>(x, embW, embB, h, hb, N);
  k_wconv2<<<8, 256, 0, stream>>>(edgeW, eWf);
  k_nnconv<<<256, 256, 0, stream>>>(nnW, WT16);
  k_hist<<<(E + 255) / 256, 256, 0, stream>>>(dst, deg, E);
  k_scan_reduce<<<nb, 256, 0, stream>>>(deg, bsum, N);
  k_scan_mid<<<1, 512, 0, stream>>>(bsum, nb);
  k_scan_final<<<nb, 256, 0, stream>>>(deg, bsum, offs, cursor, N);
  k_fill<<<(E + 255) / 256, 256, 0, stream>>>(src, dst, eattr, cursor, csrc, cattr16, E);
  k_gstart<<<(N + 255) / 256, 256, 0, stream>>>(batch, gstart, N, GG);

  int gblk = (N + 127) / 128;
  for (int l = 0; l < 4; ++l) {
    k_edge_agg<<<8192, 256, 0, stream>>>(h, (const unsigned*)hb, cattr16, csrc,
        offs, eWf + (size_t)l * 1024, edgeB + (size_t)l * 128, hpa16, cstats, N);
    k_gemm_mfma<<<gblk, 256, 0, stream>>>((const unsigned short*)hpa16,
        WT16 + (size_t)l * 128 * 128, nnB + (size_t)l * 128, hc, cstats, N);
    k_bn<<<q32, 256, 0, stream>>>(hc, cstats,
        bnG + (size_t)l * 128, bnB + (size_t)l * 128, h, (l == 3) ? nullptr : hb, N);
  }
  k_poolfinal<<<GG, 256, 0, stream>>>(h, gstart, linW, linB, out);
}